// Round 1
// baseline (320.089 us; speedup 1.0000x reference)
//
#include <hip/hip_runtime.h>
#include <stdint.h>

typedef unsigned short u16;
typedef __attribute__((ext_vector_type(8))) short bf16x8;   // 8 bf16 (4 VGPRs) MFMA A/B frag
typedef __attribute__((ext_vector_type(4))) float f32x4;    // MFMA C/D frag
typedef __attribute__((ext_vector_type(4))) int   i32x4;
typedef __attribute__((ext_vector_type(4))) unsigned short u16x4;

#define MFMA16(a, b, c) __builtin_amdgcn_mfma_f32_16x16x32_bf16((a), (b), (c), 0, 0, 0)

// ---- constants ----
#define BATCH 2
#define TSEQ  2048
#define CEMB  1024
#define NHEAD 16
#define DHEAD 64
#define BHTOT 32           // BATCH*NHEAD
#define MROWS 4096         // BATCH*TSEQ

__device__ __forceinline__ u16 bf16r(float f) {  // round-nearest-even fp32->bf16
  uint32_t u = __builtin_bit_cast(uint32_t, f);
  u += 0x7fffu + ((u >> 16) & 1u);
  return (u16)(u >> 16);
}

__device__ __forceinline__ void gl2lds16(const void* g, void* l) {
  __builtin_amdgcn_global_load_lds(
      (const __attribute__((address_space(1))) uint32_t*)g,
      (__attribute__((address_space(3))) uint32_t*)l, 16, 0, 0);
}

// ---------------- prep kernels ----------------
__global__ void conv_x(const float* __restrict__ x, u16* __restrict__ xb, int n) {
  int i = (blockIdx.x * blockDim.x + threadIdx.x) * 4;
  if (i < n) {
    f32x4 v = *(const f32x4*)(x + i);
    u16x4 o;
    o[0] = bf16r(v[0]); o[1] = bf16r(v[1]); o[2] = bf16r(v[2]); o[3] = bf16r(v[3]);
    *(u16x4*)(xb + i) = o;
  }
}

// W[K][N] (fp32) -> WT[N][K] (bf16)
__global__ void transpose_w(const float* __restrict__ W, u16* __restrict__ WT, int K, int N) {
  __shared__ float t[32][33];
  int k0 = blockIdx.y * 32, n0 = blockIdx.x * 32;
  int tx = threadIdx.x & 31, ty = threadIdx.x >> 5;   // 32 x 8
  for (int i = 0; i < 4; i++)
    t[ty + i * 8][tx] = W[(size_t)(k0 + ty + i * 8) * N + n0 + tx];
  __syncthreads();
  for (int i = 0; i < 4; i++)
    WT[(size_t)(n0 + ty + i * 8) * K + k0 + tx] = bf16r(t[tx][ty + i * 8]);
}

// ---------------- GEMM mainloop (m97 structure: 128x128 tile, BK=32) ----------------
// A[M][K], Bt[N][K] row-major bf16; 256 threads = 4 waves (2x2), each wave 64x64 out.
__device__ __forceinline__ void gemm_mainloop(const u16* __restrict__ A,
                                              const u16* __restrict__ Bt,
                                              int K, int m0, int n0,
                                              u16* AsU, u16* BsU, f32x4 acc[4][4]) {
  const int tid = threadIdx.x;
  const int wv = tid >> 6, ln = tid & 63;
  const int lr = ln & 15, lg = ln >> 4;
  const int wr = (wv >> 1) * 64, wc = (wv & 1) * 64;

  for (int mi = 0; mi < 4; mi++)
    for (int ni = 0; ni < 4; ni++) acc[mi][ni] = f32x4{0.f, 0.f, 0.f, 0.f};

  for (int k0 = 0; k0 < K; k0 += 32) {
    // stage A,B tiles: each 128x32 bf16 = 512 x 16B chunks, 2 passes x 256 threads
    for (int p = 0; p < 2; ++p) {
      int chunk = p * 256 + tid;          // == p*256 + wv*64 + ln
      int row = chunk >> 2;
      int c8  = (chunk & 3) << 3;
      // lds dest: wave-uniform base + lane*16 (hardware rule)
      u16* abase = AsU + (size_t)(p * 256 + wv * 64) * 8;
      u16* bbase = BsU + (size_t)(p * 256 + wv * 64) * 8;
      gl2lds16(A  + (size_t)(m0 + row) * K + k0 + c8, abase);
      gl2lds16(Bt + (size_t)(n0 + row) * K + k0 + c8, bbase);
    }
    __syncthreads();   // compiler drains vmcnt before s_barrier
    bf16x8 af[4], bf[4];
    for (int mi = 0; mi < 4; mi++)
      af[mi] = *(const bf16x8*)&AsU[(size_t)(wr + mi * 16 + lr) * 32 + lg * 8];
    for (int ni = 0; ni < 4; ni++)
      bf[ni] = *(const bf16x8*)&BsU[(size_t)(wc + ni * 16 + lr) * 32 + lg * 8];
    for (int mi = 0; mi < 4; mi++)
      for (int ni = 0; ni < 4; ni++)
        acc[mi][ni] = MFMA16(af[mi], bf[ni], acc[mi][ni]);
    __syncthreads();
  }
}

// ---------------- QKV GEMM: [4096x1024] @ WaT[3072x1024]^T + b -> q,k (BH,T,D), vT (BH,D,T)
__global__ __launch_bounds__(256, 2) void qkv_gemm(const u16* __restrict__ xb,
                                                   const u16* __restrict__ WaT,
                                                   const float* __restrict__ b_attn,
                                                   u16* __restrict__ qb, u16* __restrict__ kb,
                                                   u16* __restrict__ vT) {
  __shared__ u16 AsU[128 * 32];
  __shared__ u16 BsU[128 * 32];
  const int m0 = blockIdx.y * 128, n0 = blockIdx.x * 128;
  f32x4 acc[4][4];
  gemm_mainloop(xb, WaT, CEMB, m0, n0, AsU, BsU, acc);

  const int tid = threadIdx.x;
  const int wv = tid >> 6, ln = tid & 63, lr = ln & 15, lg = ln >> 4;
  const int wr = (wv >> 1) * 64, wc = (wv & 1) * 64;
  for (int mi = 0; mi < 4; mi++)
    for (int ni = 0; ni < 4; ni++) {
      int col = n0 + wc + ni * 16 + lr;               // 0..3071
      float bias = b_attn[col];
      int which = col >> 10;                          // 0=q 1=k 2=v
      int cl = col & 1023, h = cl >> 6, d = cl & 63;
      for (int j = 0; j < 4; j++) {
        int m = m0 + wr + mi * 16 + lg * 4 + j;       // 0..4095
        int b = m >> 11, t = m & 2047;
        u16 bv = bf16r(acc[mi][ni][j] + bias);
        size_t bh = (size_t)(b * NHEAD + h);
        if (which == 0)      qb[(bh * TSEQ + t) * DHEAD + d] = bv;
        else if (which == 1) kb[(bh * TSEQ + t) * DHEAD + d] = bv;
        else                 vT[(bh * DHEAD + d) * TSEQ + t] = bv;   // transposed store
      }
    }
}

// ---------------- flash attention: 4 waves x 16 q-rows per block, KB=32 ----------------
__global__ __launch_bounds__(256, 2) void attn(const u16* __restrict__ qb,
                                               const u16* __restrict__ kb,
                                               const u16* __restrict__ vT,
                                               u16* __restrict__ yb) {
  const int qblk = blockIdx.x, bh = blockIdx.y;
  const int tid = threadIdx.x, wv = tid >> 6, ln = tid & 63, lr = ln & 15, lg = ln >> 4;
  __shared__ u16 Ks[32][72];      // K tile  [k][d], padded (144B rows, 16B-multiple)
  __shared__ u16 Vs[64][40];      // V^T tile [d][k], padded (80B rows)
  __shared__ u16 Ps[4][16][40];   // per-wave P transpose buffer

  const int q0 = qblk * 64 + wv * 16;
  bf16x8 qf[2];
  {
    const u16* qrow = qb + ((size_t)bh * TSEQ + (q0 + lr)) * DHEAD + lg * 8;
    qf[0] = *(const bf16x8*)(qrow);
    qf[1] = *(const bf16x8*)(qrow + 32);
  }
  f32x4 accy[4];
  for (int i = 0; i < 4; i++) accy[i] = f32x4{0.f, 0.f, 0.f, 0.f};
  float mrun[4], lrun[4];
  for (int j = 0; j < 4; j++) { mrun[j] = -1e30f; lrun[j] = 0.f; }

  const int ntiles = qblk * 2 + 2;   // causal bound for this 64-row block
  for (int kt = 0; kt < ntiles; ++kt) {
    const int kbase = kt * 32;
    {   // stage K (32x64) and V^T (64x32), 256 x 16B each
      int row = tid >> 3, c8 = (tid & 7) << 3;
      *(i32x4*)&Ks[row][c8] =
          *(const i32x4*)(kb + ((size_t)bh * TSEQ + kbase + row) * DHEAD + c8);
      int d = tid >> 2, t8 = (tid & 3) << 3;
      *(i32x4*)&Vs[d][t8] =
          *(const i32x4*)(vT + ((size_t)bh * DHEAD + d) * TSEQ + kbase + t8);
    }
    __syncthreads();

    // S = Q K^T (two 16-col subtiles)
    f32x4 s[2];
    for (int st = 0; st < 2; ++st) {
      f32x4 z = f32x4{0.f, 0.f, 0.f, 0.f};
      bf16x8 kf0 = *(const bf16x8*)&Ks[st * 16 + lr][lg * 8];
      bf16x8 kf1 = *(const bf16x8*)&Ks[st * 16 + lr][32 + lg * 8];
      z = MFMA16(qf[0], kf0, z);
      z = MFMA16(qf[1], kf1, z);
      s[st] = z;
    }
    // scale + causal mask + online softmax (row r = lg*4+j, col = lr)
    float alpha[4];
    for (int j = 0; j < 4; j++) {
      int qg = q0 + lg * 4 + j;
      float v0 = s[0][j] * 0.125f, v1 = s[1][j] * 0.125f;
      if (kbase + lr > qg)      v0 = -1e30f;
      if (kbase + 16 + lr > qg) v1 = -1e30f;
      float mj = fmaxf(v0, v1);
      mj = fmaxf(mj, __shfl_xor(mj, 1));
      mj = fmaxf(mj, __shfl_xor(mj, 2));
      mj = fmaxf(mj, __shfl_xor(mj, 4));
      mj = fmaxf(mj, __shfl_xor(mj, 8));
      float mnew = fmaxf(mrun[j], mj);
      float a = __expf(mrun[j] - mnew);
      alpha[j] = a;
      float p0 = __expf(v0 - mnew);
      float p1 = __expf(v1 - mnew);
      s[0][j] = p0; s[1][j] = p1;
      float rs = p0 + p1;
      rs += __shfl_xor(rs, 1);
      rs += __shfl_xor(rs, 2);
      rs += __shfl_xor(rs, 4);
      rs += __shfl_xor(rs, 8);
      lrun[j] = lrun[j] * a + rs;
      mrun[j] = mnew;
    }
    for (int di = 0; di < 4; di++)
      for (int j = 0; j < 4; j++) accy[di][j] *= alpha[j];
    // P (C-layout) -> LDS -> A-layout frag; wave-local, fence instead of barrier
    for (int st = 0; st < 2; st++)
      for (int j = 0; j < 4; j++)
        Ps[wv][lg * 4 + j][st * 16 + lr] = bf16r(s[st][j]);
    __asm__ volatile("s_waitcnt lgkmcnt(0)" ::: "memory");
    bf16x8 pf = *(const bf16x8*)&Ps[wv][lr][lg * 8];
    for (int di = 0; di < 4; di++) {
      bf16x8 vf = *(const bf16x8*)&Vs[di * 16 + lr][lg * 8];
      accy[di] = MFMA16(pf, vf, accy[di]);
    }
    __syncthreads();
  }

  // epilogue: y / l -> bf16 -> yb[b][t][h*64+d]
  const int b = bh >> 4, h = bh & 15;
  for (int di = 0; di < 4; di++)
    for (int j = 0; j < 4; j++) {
      int tg = q0 + lg * 4 + j;
      float yv = accy[di][j] / lrun[j];
      yb[((size_t)b * TSEQ + tg) * CEMB + h * 64 + di * 16 + lr] = bf16r(yv);
    }
}

// ---------------- proj GEMM: yb[4096x1024] @ WpT[1024x1024]^T + b -> out fp32 ----------------
__global__ __launch_bounds__(256, 2) void proj_gemm(const u16* __restrict__ yb,
                                                    const u16* __restrict__ WpT,
                                                    const float* __restrict__ b_proj,
                                                    float* __restrict__ out) {
  __shared__ u16 AsU[128 * 32];
  __shared__ u16 BsU[128 * 32];
  const int m0 = blockIdx.y * 128, n0 = blockIdx.x * 128;
  f32x4 acc[4][4];
  gemm_mainloop(yb, WpT, CEMB, m0, n0, AsU, BsU, acc);

  const int tid = threadIdx.x;
  const int wv = tid >> 6, ln = tid & 63, lr = ln & 15, lg = ln >> 4;
  const int wr = (wv >> 1) * 64, wc = (wv & 1) * 64;
  for (int mi = 0; mi < 4; mi++)
    for (int ni = 0; ni < 4; ni++) {
      int col = n0 + wc + ni * 16 + lr;
      float bias = b_proj[col];
      for (int j = 0; j < 4; j++) {
        int m = m0 + wr + mi * 16 + lg * 4 + j;
        out[(size_t)m * CEMB + col] = acc[mi][ni][j] + bias;
      }
    }
}

// ---------------- launch ----------------
extern "C" void kernel_launch(void* const* d_in, const int* in_sizes, int n_in,
                              void* d_out, int out_size, void* d_ws, size_t ws_size,
                              hipStream_t stream) {
  const float* x      = (const float*)d_in[0];
  const float* W_attn = (const float*)d_in[1];
  const float* b_attn = (const float*)d_in[2];
  const float* W_proj = (const float*)d_in[3];
  const float* b_proj = (const float*)d_in[4];
  float* out = (float*)d_out;
  char* ws = (char*)d_ws;

  u16* xb  = (u16*)(ws);                 //  8 MB  [4096][1024] bf16
  u16* WaT = (u16*)(ws + 8388608);       //  6 MB  [3072][1024]
  u16* WpT = (u16*)(ws + 14680064);      //  2 MB  [1024][1024]
  u16* qb  = (u16*)(ws + 16777216);      //  8 MB  [BH][T][D]
  u16* kb  = (u16*)(ws + 25165824);      //  8 MB  [BH][T][D]
  u16* vT  = (u16*)(ws + 33554432);      //  8 MB  [BH][D][T]
  u16* yb  = (u16*)(ws + 41943040);      //  8 MB  [B][T][C]    (total 48 MB)

  hipLaunchKernelGGL(conv_x, dim3(4096), dim3(256), 0, stream, x, xb, MROWS * CEMB);
  hipLaunchKernelGGL(transpose_w, dim3(96, 32), dim3(256), 0, stream, W_attn, WaT, 1024, 3072);
  hipLaunchKernelGGL(transpose_w, dim3(32, 32), dim3(256), 0, stream, W_proj, WpT, 1024, 1024);
  hipLaunchKernelGGL(qkv_gemm, dim3(24, 32), dim3(256), 0, stream, xb, WaT, b_attn, qb, kb, vT);
  hipLaunchKernelGGL(attn, dim3(32, 32), dim3(256), 0, stream, qb, kb, vT, yb);
  hipLaunchKernelGGL(proj_gemm, dim3(8, 32), dim3(256), 0, stream, yb, WpT, b_proj, out);
}

// Round 6
// 226.180 us; speedup vs baseline: 1.4152x; 1.4152x over previous
//
#include <hip/hip_runtime.h>
#include <stdint.h>

typedef unsigned short u16;
typedef __attribute__((ext_vector_type(8))) short bf16x8;   // 8 bf16 (4 VGPRs) MFMA A/B frag
typedef __attribute__((ext_vector_type(4))) float f32x4;    // MFMA C/D frag
typedef __attribute__((ext_vector_type(4))) int   i32x4;
typedef __attribute__((ext_vector_type(4))) unsigned short u16x4;

#define MFMA16(a, b, c) __builtin_amdgcn_mfma_f32_16x16x32_bf16((a), (b), (c), 0, 0, 0)

// ---- constants ----
#define BATCH 2
#define TSEQ  2048
#define CEMB  1024
#define NHEAD 16
#define DHEAD 64
#define BHTOT 32           // BATCH*NHEAD
#define MROWS 4096         // BATCH*TSEQ

__device__ __forceinline__ u16 bf16r(float f) {  // round-nearest-even fp32->bf16
  uint32_t u = __builtin_bit_cast(uint32_t, f);
  u += 0x7fffu + ((u >> 16) & 1u);
  return (u16)(u >> 16);
}

__device__ __forceinline__ void gl2lds16(const void* g, void* l) {
  __builtin_amdgcn_global_load_lds(
      (const __attribute__((address_space(1))) uint32_t*)g,
      (__attribute__((address_space(3))) uint32_t*)l, 16, 0, 0);
}

// ---------------- prep kernels ----------------
__global__ void conv_x(const float* __restrict__ x, u16* __restrict__ xb, int n) {
  int i = (blockIdx.x * blockDim.x + threadIdx.x) * 4;
  if (i < n) {
    f32x4 v = *(const f32x4*)(x + i);
    u16x4 o;
    o[0] = bf16r(v[0]); o[1] = bf16r(v[1]); o[2] = bf16r(v[2]); o[3] = bf16r(v[3]);
    *(u16x4*)(xb + i) = o;
  }
}

// W[K][N] (fp32) -> WT[N][K] (bf16)
__global__ void transpose_w(const float* __restrict__ W, u16* __restrict__ WT, int K, int N) {
  __shared__ float t[32][33];
  int k0 = blockIdx.y * 32, n0 = blockIdx.x * 32;
  int tx = threadIdx.x & 31, ty = threadIdx.x >> 5;   // 32 x 8
  for (int i = 0; i < 4; i++)
    t[ty + i * 8][tx] = W[(size_t)(k0 + ty + i * 8) * N + n0 + tx];
  __syncthreads();
  for (int i = 0; i < 4; i++)
    WT[(size_t)(n0 + ty + i * 8) * K + k0 + tx] = bf16r(t[tx][ty + i * 8]);
}

// ---------------- GEMM mainloop (m97 structure: 128x128 tile, BK=32) ----------------
__device__ __forceinline__ void gemm_mainloop(const u16* __restrict__ A,
                                              const u16* __restrict__ Bt,
                                              int K, int m0, int n0,
                                              u16* AsU, u16* BsU, f32x4 acc[4][4]) {
  const int tid = threadIdx.x;
  const int wv = tid >> 6, ln = tid & 63;
  const int lr = ln & 15, lg = ln >> 4;
  const int wr = (wv >> 1) * 64, wc = (wv & 1) * 64;

  for (int mi = 0; mi < 4; mi++)
    for (int ni = 0; ni < 4; ni++) acc[mi][ni] = f32x4{0.f, 0.f, 0.f, 0.f};

  for (int k0 = 0; k0 < K; k0 += 32) {
    for (int p = 0; p < 2; ++p) {
      int chunk = p * 256 + tid;
      int row = chunk >> 2;
      int c8  = (chunk & 3) << 3;
      u16* abase = AsU + (size_t)(p * 256 + wv * 64) * 8;
      u16* bbase = BsU + (size_t)(p * 256 + wv * 64) * 8;
      gl2lds16(A  + (size_t)(m0 + row) * K + k0 + c8, abase);
      gl2lds16(Bt + (size_t)(n0 + row) * K + k0 + c8, bbase);
    }
    __syncthreads();
    bf16x8 af[4], bf[4];
    for (int mi = 0; mi < 4; mi++)
      af[mi] = *(const bf16x8*)&AsU[(size_t)(wr + mi * 16 + lr) * 32 + lg * 8];
    for (int ni = 0; ni < 4; ni++)
      bf[ni] = *(const bf16x8*)&BsU[(size_t)(wc + ni * 16 + lr) * 32 + lg * 8];
    for (int mi = 0; mi < 4; mi++)
      for (int ni = 0; ni < 4; ni++)
        acc[mi][ni] = MFMA16(af[mi], bf[ni], acc[mi][ni]);
    __syncthreads();
  }
}

// ---------------- QKV GEMM ----------------
__global__ __launch_bounds__(256, 2) void qkv_gemm(const u16* __restrict__ xb,
                                                   const u16* __restrict__ WaT,
                                                   const float* __restrict__ b_attn,
                                                   u16* __restrict__ qb, u16* __restrict__ kb,
                                                   u16* __restrict__ vT) {
  __shared__ u16 AsU[128 * 32];
  __shared__ u16 BsU[128 * 32];
  const int m0 = blockIdx.y * 128, n0 = blockIdx.x * 128;
  f32x4 acc[4][4];
  gemm_mainloop(xb, WaT, CEMB, m0, n0, AsU, BsU, acc);

  const int tid = threadIdx.x;
  const int wv = tid >> 6, ln = tid & 63, lr = ln & 15, lg = ln >> 4;
  const int wr = (wv >> 1) * 64, wc = (wv & 1) * 64;
  for (int mi = 0; mi < 4; mi++)
    for (int ni = 0; ni < 4; ni++) {
      int col = n0 + wc + ni * 16 + lr;               // 0..3071
      float bias = b_attn[col];
      int which = col >> 10;                          // 0=q 1=k 2=v
      int cl = col & 1023, h = cl >> 6, d = cl & 63;
      for (int j = 0; j < 4; j++) {
        int m = m0 + wr + mi * 16 + lg * 4 + j;       // 0..4095
        int b = m >> 11, t = m & 2047;
        u16 bv = bf16r(acc[mi][ni][j] + bias);
        size_t bh = (size_t)(b * NHEAD + h);
        if (which == 0)      qb[(bh * TSEQ + t) * DHEAD + d] = bv;
        else if (which == 1) kb[(bh * TSEQ + t) * DHEAD + d] = bv;
        else                 vT[(bh * DHEAD + d) * TSEQ + t] = bv;   // transposed store
      }
    }
}

// ---------------- flash attention v2 ----------------
// Swapped-operand design: S^T = mfma(K,Q) puts q on C-cols (lane&15) -> softmax
// state is lane-local. PV computes y^T = mfma(V^T, P) keeping q on cols.
// 4 waves x 32 q-rows = 128 q/block; KVBLK=64; T14 reg-staged prefetch.
__global__ __launch_bounds__(256, 2) void attn(const u16* __restrict__ qb,
                                               const u16* __restrict__ kb,
                                               const u16* __restrict__ vT,
                                               u16* __restrict__ yb) {
  const int flat = blockIdx.x;                    // 512 blocks
  const int myid = (flat & 7) * 64 + (flat >> 3); // XCD swizzle: 4 heads per XCD
  const int bh = myid >> 4, qblk = myid & 15;
  const int tid = threadIdx.x, wv = tid >> 6, ln = tid & 63, lr = ln & 15, lg = ln >> 4;

  __shared__ u16 Ks[64][72];          // K tile [k][d], +8 pad (2-way max)
  __shared__ u16 Vs[64][72];          // V^T tile [d][k], +8 pad
  __shared__ u16 Ps[4][2][16][72];    // per-wave P buffer [qsub][q][k], +8 pad

  const int wq0 = qblk * 128 + wv * 32;
  const float SCL = 0.125f * 1.44269504f;   // 1/sqrt(64) * log2(e), exp2 domain

  // hoist Q fragments (B operand: lane lr = q-col, lg*8 = d-slice)
  bf16x8 qf[2][2];
#pragma unroll
  for (int qs = 0; qs < 2; qs++) {
    const u16* qrow = qb + ((size_t)bh * TSEQ + (wq0 + qs * 16 + lr)) * DHEAD + lg * 8;
    qf[qs][0] = *(const bf16x8*)(qrow);
    qf[qs][1] = *(const bf16x8*)(qrow + 32);
  }

  f32x4 acc[2][4];
#pragma unroll
  for (int qs = 0; qs < 2; qs++)
#pragma unroll
    for (int df = 0; df < 4; df++) acc[qs][df] = f32x4{0.f, 0.f, 0.f, 0.f};
  float mrun[2] = {-1e30f, -1e30f}, lrun[2] = {0.f, 0.f};

  const int ntiles = 2 * qblk + 2;
  const int srow = tid >> 3, sc8 = (tid & 7) << 3;   // staging: 8 lanes/row

  i32x4 kreg[2], vreg[2];
#pragma unroll
  for (int p = 0; p < 2; p++) {                      // prologue: tile 0
    int row = p * 32 + srow;
    kreg[p] = *(const i32x4*)(kb + ((size_t)bh * TSEQ + row) * DHEAD + sc8);
    vreg[p] = *(const i32x4*)(vT + ((size_t)bh * DHEAD + row) * TSEQ + sc8);
  }

  for (int kt = 0; kt < ntiles; kt++) {
    const int kbase = kt * 64;
#pragma unroll
    for (int p = 0; p < 2; p++) {
      int row = p * 32 + srow;
      *(i32x4*)&Ks[row][sc8] = kreg[p];
      *(i32x4*)&Vs[row][sc8] = vreg[p];
    }
    __syncthreads();
    if (kt + 1 < ntiles) {                           // T14: prefetch next tile
      const int nb = kbase + 64;
#pragma unroll
      for (int p = 0; p < 2; p++) {
        int row = p * 32 + srow;
        kreg[p] = *(const i32x4*)(kb + ((size_t)bh * TSEQ + nb + row) * DHEAD + sc8);
        vreg[p] = *(const i32x4*)(vT + ((size_t)bh * DHEAD + row) * TSEQ + nb + sc8);
      }
    }

    // S^T = K Q^T : 16 MFMA
    f32x4 s[2][4];
#pragma unroll
    for (int st = 0; st < 4; st++) {
      bf16x8 kf0 = *(const bf16x8*)&Ks[st * 16 + lr][lg * 8];
      bf16x8 kf1 = *(const bf16x8*)&Ks[st * 16 + lr][32 + lg * 8];
#pragma unroll
      for (int qs = 0; qs < 2; qs++) {
        f32x4 z = f32x4{0.f, 0.f, 0.f, 0.f};
        z = MFMA16(kf0, qf[qs][0], z);
        z = MFMA16(kf1, qf[qs][1], z);
        s[qs][st] = z;
      }
    }

    // online softmax: lane owns q = wq0 + qs*16 + lr; 16 k-values in-lane
#pragma unroll
    for (int qs = 0; qs < 2; qs++) {
      const int qg = wq0 + qs * 16 + lr;
      float mt = -1e30f;
#pragma unroll
      for (int st = 0; st < 4; st++)
#pragma unroll
        for (int j = 0; j < 4; j++) {
          int kg = kbase + st * 16 + lg * 4 + j;
          float v = (kg <= qg) ? s[qs][st][j] * SCL : -1e30f;
          s[qs][st][j] = v;
          mt = fmaxf(mt, v);
        }
      mt = fmaxf(mt, __shfl_xor(mt, 16));
      mt = fmaxf(mt, __shfl_xor(mt, 32));
      float mnew = fmaxf(mrun[qs], mt);
      float al = __builtin_amdgcn_exp2f(mrun[qs] - mnew);
      float rs = 0.f;
#pragma unroll
      for (int st = 0; st < 4; st++)
#pragma unroll
        for (int j = 0; j < 4; j++) {
          float p = __builtin_amdgcn_exp2f(s[qs][st][j] - mnew);
          s[qs][st][j] = p;
          rs += p;
        }
      rs += __shfl_xor(rs, 16);
      rs += __shfl_xor(rs, 32);
      lrun[qs] = lrun[qs] * al + rs;
      mrun[qs] = mnew;
#pragma unroll
      for (int df = 0; df < 4; df++)
#pragma unroll
        for (int j = 0; j < 4; j++) acc[qs][df][j] *= al;
      // P -> Ps (wave-local), packed u32 stores
#pragma unroll
      for (int st = 0; st < 4; st++) {
        uint32_t w0 = (uint32_t)bf16r(s[qs][st][0]) | ((uint32_t)bf16r(s[qs][st][1]) << 16);
        uint32_t w1 = (uint32_t)bf16r(s[qs][st][2]) | ((uint32_t)bf16r(s[qs][st][3]) << 16);
        *(uint32_t*)&Ps[wv][qs][lr][st * 16 + lg * 4]     = w0;
        *(uint32_t*)&Ps[wv][qs][lr][st * 16 + lg * 4 + 2] = w1;
      }
    }
    __asm__ volatile("s_waitcnt lgkmcnt(0)" ::: "memory");
    __builtin_amdgcn_sched_barrier(0);

    // y^T += V^T P : 16 MFMA
    bf16x8 pf[2][2];
#pragma unroll
    for (int qs = 0; qs < 2; qs++)
#pragma unroll
      for (int ks = 0; ks < 2; ks++)
        pf[qs][ks] = *(const bf16x8*)&Ps[wv][qs][lr][ks * 32 + lg * 8];
#pragma unroll
    for (int df = 0; df < 4; df++)
#pragma unroll
      for (int ks = 0; ks < 2; ks++) {
        bf16x8 vf = *(const bf16x8*)&Vs[df * 16 + lr][ks * 32 + lg * 8];
        acc[0][df] = MFMA16(vf, pf[0][ks], acc[0][df]);
        acc[1][df] = MFMA16(vf, pf[1][ks], acc[1][df]);
      }
    __syncthreads();
  }

  // epilogue: y = acc / l -> yb[b][t][h*64+d]
  const int b = bh >> 4, h = bh & 15;
#pragma unroll
  for (int qs = 0; qs < 2; qs++) {
    float inv = 1.f / lrun[qs];
    int tg = wq0 + qs * 16 + lr;
#pragma unroll
    for (int df = 0; df < 4; df++) {
      u16x4 o;
#pragma unroll
      for (int j = 0; j < 4; j++) o[j] = bf16r(acc[qs][df][j] * inv);
      *(u16x4*)&yb[((size_t)b * TSEQ + tg) * CEMB + h * 64 + df * 16 + lg * 4] = o;
    }
  }
}

// ---------------- proj GEMM ----------------
__global__ __launch_bounds__(256, 2) void proj_gemm(const u16* __restrict__ yb,
                                                    const u16* __restrict__ WpT,
                                                    const float* __restrict__ b_proj,
                                                    float* __restrict__ out) {
  __shared__ u16 AsU[128 * 32];
  __shared__ u16 BsU[128 * 32];
  const int m0 = blockIdx.y * 128, n0 = blockIdx.x * 128;
  f32x4 acc[4][4];
  gemm_mainloop(yb, WpT, CEMB, m0, n0, AsU, BsU, acc);

  const int tid = threadIdx.x;
  const int wv = tid >> 6, ln = tid & 63, lr = ln & 15, lg = ln >> 4;
  const int wr = (wv >> 1) * 64, wc = (wv & 1) * 64;
  for (int mi = 0; mi < 4; mi++)
    for (int ni = 0; ni < 4; ni++) {
      int col = n0 + wc + ni * 16 + lr;
      float bias = b_proj[col];
      for (int j = 0; j < 4; j++) {
        int m = m0 + wr + mi * 16 + lg * 4 + j;
        out[(size_t)m * CEMB + col] = acc[mi][ni][j] + bias;
      }
    }
}

// ---------------- launch ----------------
extern "C" void kernel_launch(void* const* d_in, const int* in_sizes, int n_in,
                              void* d_out, int out_size, void* d_ws, size_t ws_size,
                              hipStream_t stream) {
  const float* x      = (const float*)d_in[0];
  const float* W_attn = (const float*)d_in[1];
  const float* b_attn = (const float*)d_in[2];
  const float* W_proj = (const float*)d_in[3];
  const float* b_proj = (const float*)d_in[4];
  float* out = (float*)d_out;
  char* ws = (char*)d_ws;

  u16* xb  = (u16*)(ws);                 //  8 MB  [4096][1024] bf16
  u16* WaT = (u16*)(ws + 8388608);       //  6 MB  [3072][1024]
  u16* WpT = (u16*)(ws + 14680064);      //  2 MB  [1024][1024]
  u16* qb  = (u16*)(ws + 16777216);      //  8 MB  [BH][T][D]
  u16* kb  = (u16*)(ws + 25165824);      //  8 MB  [BH][T][D]
  u16* vT  = (u16*)(ws + 33554432);      //  8 MB  [BH][D][T]
  u16* yb  = (u16*)(ws + 41943040);      //  8 MB  [B][T][C]

  hipLaunchKernelGGL(conv_x, dim3(4096), dim3(256), 0, stream, x, xb, MROWS * CEMB);
  hipLaunchKernelGGL(transpose_w, dim3(96, 32), dim3(256), 0, stream, W_attn, WaT, 1024, 3072);
  hipLaunchKernelGGL(transpose_w, dim3(32, 32), dim3(256), 0, stream, W_proj, WpT, 1024, 1024);
  hipLaunchKernelGGL(qkv_gemm, dim3(24, 32), dim3(256), 0, stream, xb, WaT, b_attn, qb, kb, vT);
  hipLaunchKernelGGL(attn, dim3(512), dim3(256), 0, stream, qb, kb, vT, yb);
  hipLaunchKernelGGL(proj_gemm, dim3(8, 32), dim3(256), 0, stream, yb, WpT, b_proj, out);
}

// Round 7
// 202.604 us; speedup vs baseline: 1.5799x; 1.1164x over previous
//
#include <hip/hip_runtime.h>
#include <stdint.h>

typedef unsigned short u16;
typedef __attribute__((ext_vector_type(8))) short bf16x8;   // 8 bf16 (4 VGPRs) MFMA A/B frag
typedef __attribute__((ext_vector_type(4))) float f32x4;    // MFMA C/D frag
typedef __attribute__((ext_vector_type(4))) int   i32x4;
typedef __attribute__((ext_vector_type(4))) unsigned short u16x4;

#define MFMA16(a, b, c) __builtin_amdgcn_mfma_f32_16x16x32_bf16((a), (b), (c), 0, 0, 0)

// ---- constants ----
#define BATCH 2
#define TSEQ  2048
#define CEMB  1024
#define NHEAD 16
#define DHEAD 64
#define BHTOT 32           // BATCH*NHEAD
#define MROWS 4096         // BATCH*TSEQ

__device__ __forceinline__ u16 bf16r(float f) {  // round-nearest-even fp32->bf16
  uint32_t u = __builtin_bit_cast(uint32_t, f);
  u += 0x7fffu + ((u >> 16) & 1u);
  return (u16)(u >> 16);
}

__device__ __forceinline__ float bf2f(short v) {
  return __builtin_bit_cast(float, ((uint32_t)(u16)v) << 16);
}

__device__ __forceinline__ bf16x8 scale8(bf16x8 a, float s) {
  bf16x8 r;
#pragma unroll
  for (int i = 0; i < 8; i++) r[i] = (short)bf16r(bf2f(a[i]) * s);
  return r;
}

__device__ __forceinline__ void gl2lds16(const void* g, void* l) {
  __builtin_amdgcn_global_load_lds(
      (const __attribute__((address_space(1))) uint32_t*)g,
      (__attribute__((address_space(3))) uint32_t*)l, 16, 0, 0);
}

// ---------------- prep kernels ----------------
__global__ void conv_x(const float* __restrict__ x, u16* __restrict__ xb, int n) {
  int i = (blockIdx.x * blockDim.x + threadIdx.x) * 4;
  if (i < n) {
    f32x4 v = *(const f32x4*)(x + i);
    u16x4 o;
    o[0] = bf16r(v[0]); o[1] = bf16r(v[1]); o[2] = bf16r(v[2]); o[3] = bf16r(v[3]);
    *(u16x4*)(xb + i) = o;
  }
}

// W[K][N] (fp32) -> WT[N][K] (bf16)
__global__ void transpose_w(const float* __restrict__ W, u16* __restrict__ WT, int K, int N) {
  __shared__ float t[32][33];
  int k0 = blockIdx.y * 32, n0 = blockIdx.x * 32;
  int tx = threadIdx.x & 31, ty = threadIdx.x >> 5;   // 32 x 8
  for (int i = 0; i < 4; i++)
    t[ty + i * 8][tx] = W[(size_t)(k0 + ty + i * 8) * N + n0 + tx];
  __syncthreads();
  for (int i = 0; i < 4; i++)
    WT[(size_t)(n0 + ty + i * 8) * K + k0 + tx] = bf16r(t[tx][ty + i * 8]);
}

// ---------------- GEMM mainloop (m97 structure: 128x128 tile, BK=32) ----------------
__device__ __forceinline__ void gemm_mainloop(const u16* __restrict__ A,
                                              const u16* __restrict__ Bt,
                                              int K, int m0, int n0,
                                              u16* AsU, u16* BsU, f32x4 acc[4][4]) {
  const int tid = threadIdx.x;
  const int wv = tid >> 6, ln = tid & 63;
  const int lr = ln & 15, lg = ln >> 4;
  const int wr = (wv >> 1) * 64, wc = (wv & 1) * 64;

  for (int mi = 0; mi < 4; mi++)
    for (int ni = 0; ni < 4; ni++) acc[mi][ni] = f32x4{0.f, 0.f, 0.f, 0.f};

  for (int k0 = 0; k0 < K; k0 += 32) {
    for (int p = 0; p < 2; ++p) {
      int chunk = p * 256 + tid;
      int row = chunk >> 2;
      int c8  = (chunk & 3) << 3;
      u16* abase = AsU + (size_t)(p * 256 + wv * 64) * 8;
      u16* bbase = BsU + (size_t)(p * 256 + wv * 64) * 8;
      gl2lds16(A  + (size_t)(m0 + row) * K + k0 + c8, abase);
      gl2lds16(Bt + (size_t)(n0 + row) * K + k0 + c8, bbase);
    }
    __syncthreads();
    bf16x8 af[4], bf[4];
    for (int mi = 0; mi < 4; mi++)
      af[mi] = *(const bf16x8*)&AsU[(size_t)(wr + mi * 16 + lr) * 32 + lg * 8];
    for (int ni = 0; ni < 4; ni++)
      bf[ni] = *(const bf16x8*)&BsU[(size_t)(wc + ni * 16 + lr) * 32 + lg * 8];
    for (int mi = 0; mi < 4; mi++)
      for (int ni = 0; ni < 4; ni++)
        acc[mi][ni] = MFMA16(af[mi], bf[ni], acc[mi][ni]);
    __syncthreads();
  }
}

// ---------------- QKV GEMM ----------------
__global__ __launch_bounds__(256, 2) void qkv_gemm(const u16* __restrict__ xb,
                                                   const u16* __restrict__ WaT,
                                                   const float* __restrict__ b_attn,
                                                   u16* __restrict__ qb, u16* __restrict__ kb,
                                                   u16* __restrict__ vT) {
  __shared__ u16 AsU[128 * 32];
  __shared__ u16 BsU[128 * 32];
  const int m0 = blockIdx.y * 128, n0 = blockIdx.x * 128;
  f32x4 acc[4][4];
  gemm_mainloop(xb, WaT, CEMB, m0, n0, AsU, BsU, acc);

  const int tid = threadIdx.x;
  const int wv = tid >> 6, ln = tid & 63, lr = ln & 15, lg = ln >> 4;
  const int wr = (wv >> 1) * 64, wc = (wv & 1) * 64;
  for (int mi = 0; mi < 4; mi++)
    for (int ni = 0; ni < 4; ni++) {
      int col = n0 + wc + ni * 16 + lr;               // 0..3071
      float bias = b_attn[col];
      int which = col >> 10;                          // 0=q 1=k 2=v
      int cl = col & 1023, h = cl >> 6, d = cl & 63;
      for (int j = 0; j < 4; j++) {
        int m = m0 + wr + mi * 16 + lg * 4 + j;       // 0..4095
        int b = m >> 11, t = m & 2047;
        u16 bv = bf16r(acc[mi][ni][j] + bias);
        size_t bh = (size_t)(b * NHEAD + h);
        if (which == 0)      qb[(bh * TSEQ + t) * DHEAD + d] = bv;
        else if (which == 1) kb[(bh * TSEQ + t) * DHEAD + d] = bv;
        else                 vT[(bh * DHEAD + d) * TSEQ + t] = bv;   // transposed store
      }
    }
}

// ---------------- flash attention v3 ----------------
// v2 post-mortem: latency-bound (Occ 10%, all pipes idle). v3 changes:
//  (1) LPT + CU-pair block mapping: long halves (qblk 15..8) dispatch first;
//      block i and i+256 share a CU (round-robin), same bh, uniform 36 tiles.
//  (2) K/V double-buffered LDS -> ONE barrier per tile; stage-writes overlap
//      QK/softmax (T14). (3) SCL folded into Q frags; causal sel only on
//      diagonal tiles; rescale skipped when no new max (T13, THR=0).
__global__ __launch_bounds__(256, 2) void attn(const u16* __restrict__ qb,
                                               const u16* __restrict__ kb,
                                               const u16* __restrict__ vT,
                                               u16* __restrict__ yb) {
  const int flat = blockIdx.x;                  // 512 blocks
  const int x = flat & 7;                       // XCD id: 4 heads per XCD
  const int l = flat >> 3;                      // 0..63 within XCD
  int bh, qblk;
  if (l < 32) { bh = 4 * x + (l >> 3); qblk = 15 - (l & 7); }   // long first
  else        { int l2 = l - 32; bh = 4 * x + (l2 >> 3); qblk = l2 & 7; }
  const int tid = threadIdx.x, wv = tid >> 6, ln = tid & 63, lr = ln & 15, lg = ln >> 4;

  __shared__ u16 Ks[2][64][72];       // K tile [k][d], dbuf, +8 pad
  __shared__ u16 Vs[2][64][72];       // V^T tile [d][k], dbuf, +8 pad
  __shared__ u16 Ps[4][2][16][72];    // per-wave P buffer [qsub][q][k], +8 pad

  const int wq0 = qblk * 128 + wv * 32;
  const float SCL = 0.125f * 1.44269504f;   // 1/sqrt(64) * log2(e)

  // hoist Q fragments, pre-scaled by SCL (B operand: lr = q-col, lg*8 = d-slice)
  bf16x8 qf[2][2];
#pragma unroll
  for (int qs = 0; qs < 2; qs++) {
    const u16* qrow = qb + ((size_t)bh * TSEQ + (wq0 + qs * 16 + lr)) * DHEAD + lg * 8;
    qf[qs][0] = scale8(*(const bf16x8*)(qrow), SCL);
    qf[qs][1] = scale8(*(const bf16x8*)(qrow + 32), SCL);
  }

  f32x4 acc[2][4];
#pragma unroll
  for (int qs = 0; qs < 2; qs++)
#pragma unroll
    for (int df = 0; df < 4; df++) acc[qs][df] = f32x4{0.f, 0.f, 0.f, 0.f};
  float mrun[2] = {-1e30f, -1e30f}, lrun[2] = {0.f, 0.f};

  const int ntiles = 2 * qblk + 2;
  const int srow = tid >> 3, sc8 = (tid & 7) << 3;   // staging: 8 lanes/row

  // prologue: tile 0 -> LDS buf0 directly; issue tile 1 -> regs
  i32x4 kreg[2], vreg[2];
#pragma unroll
  for (int p = 0; p < 2; p++) {
    int row = p * 32 + srow;
    i32x4 k0 = *(const i32x4*)(kb + ((size_t)bh * TSEQ + row) * DHEAD + sc8);
    i32x4 v0 = *(const i32x4*)(vT + ((size_t)bh * DHEAD + row) * TSEQ + sc8);
    *(i32x4*)&Ks[0][row][sc8] = k0;
    *(i32x4*)&Vs[0][row][sc8] = v0;
  }
#pragma unroll
  for (int p = 0; p < 2; p++) {
    int row = p * 32 + srow;
    kreg[p] = *(const i32x4*)(kb + ((size_t)bh * TSEQ + 64 + row) * DHEAD + sc8);
    vreg[p] = *(const i32x4*)(vT + ((size_t)bh * DHEAD + row) * TSEQ + 64 + sc8);
  }

  int c = 0;
  for (int kt = 0; kt < ntiles; kt++) {
    const int kbase = kt * 64;
    __syncthreads();   // buf[c] writes visible; prior reads of buf[c^1] done

    // S^T = K Q^T on buf[c] : 16 MFMA
    f32x4 s[2][4];
#pragma unroll
    for (int st = 0; st < 4; st++) {
      bf16x8 kf0 = *(const bf16x8*)&Ks[c][st * 16 + lr][lg * 8];
      bf16x8 kf1 = *(const bf16x8*)&Ks[c][st * 16 + lr][32 + lg * 8];
#pragma unroll
      for (int qs = 0; qs < 2; qs++) {
        f32x4 z = f32x4{0.f, 0.f, 0.f, 0.f};
        z = MFMA16(kf0, qf[qs][0], z);
        z = MFMA16(kf1, qf[qs][1], z);
        s[qs][st] = z;
      }
    }

    // stage tile kt+1 into buf[c^1] (write-late; vmcnt wait hides under QK)
    if (kt + 1 < ntiles) {
#pragma unroll
      for (int p = 0; p < 2; p++) {
        int row = p * 32 + srow;
        *(i32x4*)&Ks[c ^ 1][row][sc8] = kreg[p];
        *(i32x4*)&Vs[c ^ 1][row][sc8] = vreg[p];
      }
    }
    // issue prefetch of tile kt+2
    if (kt + 2 < ntiles) {
      const int nb = kbase + 128;
#pragma unroll
      for (int p = 0; p < 2; p++) {
        int row = p * 32 + srow;
        kreg[p] = *(const i32x4*)(kb + ((size_t)bh * TSEQ + nb + row) * DHEAD + sc8);
        vreg[p] = *(const i32x4*)(vT + ((size_t)bh * DHEAD + row) * TSEQ + nb + sc8);
      }
    }

    // online softmax: lane owns q = wq0 + qs*16 + lr; 16 k-values in-lane
#pragma unroll
    for (int qs = 0; qs < 2; qs++) {
      const int qgmin = wq0 + qs * 16;
      float mt = -1e30f;
      if (kbase + 63 <= qgmin) {          // fully-unmasked tile (wave-uniform)
#pragma unroll
        for (int st = 0; st < 4; st++)
#pragma unroll
          for (int j = 0; j < 4; j++) mt = fmaxf(mt, s[qs][st][j]);
      } else {                             // diagonal tile: causal select
        const int qg = qgmin + lr;
#pragma unroll
        for (int st = 0; st < 4; st++)
#pragma unroll
          for (int j = 0; j < 4; j++) {
            int kg = kbase + st * 16 + lg * 4 + j;
            float v = (kg <= qg) ? s[qs][st][j] : -1e30f;
            s[qs][st][j] = v;
            mt = fmaxf(mt, v);
          }
      }
      mt = fmaxf(mt, __shfl_xor(mt, 16));
      mt = fmaxf(mt, __shfl_xor(mt, 32));
      if (!__all(mt <= mrun[qs])) {        // T13: skip rescale when max stable
        float mnew = fmaxf(mrun[qs], mt);
        float al = __builtin_amdgcn_exp2f(mrun[qs] - mnew);
#pragma unroll
        for (int df = 0; df < 4; df++)
#pragma unroll
          for (int j = 0; j < 4; j++) acc[qs][df][j] *= al;
        lrun[qs] *= al;
        mrun[qs] = mnew;
      }
      float rs = 0.f;
#pragma unroll
      for (int st = 0; st < 4; st++)
#pragma unroll
        for (int j = 0; j < 4; j++) {
          float p = __builtin_amdgcn_exp2f(s[qs][st][j] - mrun[qs]);
          s[qs][st][j] = p;
          rs += p;
        }
      rs += __shfl_xor(rs, 16);
      rs += __shfl_xor(rs, 32);
      lrun[qs] += rs;
      // P -> Ps (wave-local), packed u32 stores
#pragma unroll
      for (int st = 0; st < 4; st++) {
        uint32_t w0 = (uint32_t)bf16r(s[qs][st][0]) | ((uint32_t)bf16r(s[qs][st][1]) << 16);
        uint32_t w1 = (uint32_t)bf16r(s[qs][st][2]) | ((uint32_t)bf16r(s[qs][st][3]) << 16);
        *(uint32_t*)&Ps[wv][qs][lr][st * 16 + lg * 4]     = w0;
        *(uint32_t*)&Ps[wv][qs][lr][st * 16 + lg * 4 + 2] = w1;
      }
    }
    __asm__ volatile("s_waitcnt lgkmcnt(0)" ::: "memory");
    __builtin_amdgcn_sched_barrier(0);

    // y^T += V^T P on buf[c] : 16 MFMA
    bf16x8 pf[2][2];
#pragma unroll
    for (int qs = 0; qs < 2; qs++)
#pragma unroll
      for (int ks = 0; ks < 2; ks++)
        pf[qs][ks] = *(const bf16x8*)&Ps[wv][qs][lr][ks * 32 + lg * 8];
#pragma unroll
    for (int df = 0; df < 4; df++)
#pragma unroll
      for (int ks = 0; ks < 2; ks++) {
        bf16x8 vf = *(const bf16x8*)&Vs[c][df * 16 + lr][ks * 32 + lg * 8];
        acc[0][df] = MFMA16(vf, pf[0][ks], acc[0][df]);
        acc[1][df] = MFMA16(vf, pf[1][ks], acc[1][df]);
      }
    c ^= 1;
  }

  // epilogue: y = acc / l -> yb[b][t][h*64+d]
  const int b = bh >> 4, h = bh & 15;
#pragma unroll
  for (int qs = 0; qs < 2; qs++) {
    float inv = 1.f / lrun[qs];
    int tg = wq0 + qs * 16 + lr;
#pragma unroll
    for (int df = 0; df < 4; df++) {
      u16x4 o;
#pragma unroll
      for (int j = 0; j < 4; j++) o[j] = bf16r(acc[qs][df][j] * inv);
      *(u16x4*)&yb[((size_t)b * TSEQ + tg) * CEMB + h * 64 + df * 16 + lg * 4] = o;
    }
  }
}

// ---------------- proj GEMM ----------------
__global__ __launch_bounds__(256, 2) void proj_gemm(const u16* __restrict__ yb,
                                                    const u16* __restrict__ WpT,
                                                    const float* __restrict__ b_proj,
                                                    float* __restrict__ out) {
  __shared__ u16 AsU[128 * 32];
  __shared__ u16 BsU[128 * 32];
  const int m0 = blockIdx.y * 128, n0 = blockIdx.x * 128;
  f32x4 acc[4][4];
  gemm_mainloop(yb, WpT, CEMB, m0, n0, AsU, BsU, acc);

  const int tid = threadIdx.x;
  const int wv = tid >> 6, ln = tid & 63, lr = ln & 15, lg = ln >> 4;
  const int wr = (wv >> 1) * 64, wc = (wv & 1) * 64;
  for (int mi = 0; mi < 4; mi++)
    for (int ni = 0; ni < 4; ni++) {
      int col = n0 + wc + ni * 16 + lr;
      float bias = b_proj[col];
      for (int j = 0; j < 4; j++) {
        int m = m0 + wr + mi * 16 + lg * 4 + j;
        out[(size_t)m * CEMB + col] = acc[mi][ni][j] + bias;
      }
    }
}

// ---------------- launch ----------------
extern "C" void kernel_launch(void* const* d_in, const int* in_sizes, int n_in,
                              void* d_out, int out_size, void* d_ws, size_t ws_size,
                              hipStream_t stream) {
  const float* x      = (const float*)d_in[0];
  const float* W_attn = (const float*)d_in[1];
  const float* b_attn = (const float*)d_in[2];
  const float* W_proj = (const float*)d_in[3];
  const float* b_proj = (const float*)d_in[4];
  float* out = (float*)d_out;
  char* ws = (char*)d_ws;

  u16* xb  = (u16*)(ws);                 //  8 MB  [4096][1024] bf16
  u16* WaT = (u16*)(ws + 8388608);       //  6 MB  [3072][1024]
  u16* WpT = (u16*)(ws + 14680064);      //  2 MB  [1024][1024]
  u16* qb  = (u16*)(ws + 16777216);      //  8 MB  [BH][T][D]
  u16* kb  = (u16*)(ws + 25165824);      //  8 MB  [BH][T][D]
  u16* vT  = (u16*)(ws + 33554432);      //  8 MB  [BH][D][T]
  u16* yb  = (u16*)(ws + 41943040);      //  8 MB  [B][T][C]

  hipLaunchKernelGGL(conv_x, dim3(4096), dim3(256), 0, stream, x, xb, MROWS * CEMB);
  hipLaunchKernelGGL(transpose_w, dim3(96, 32), dim3(256), 0, stream, W_attn, WaT, 1024, 3072);
  hipLaunchKernelGGL(transpose_w, dim3(32, 32), dim3(256), 0, stream, W_proj, WpT, 1024, 1024);
  hipLaunchKernelGGL(qkv_gemm, dim3(24, 32), dim3(256), 0, stream, xb, WaT, b_attn, qb, kb, vT);
  hipLaunchKernelGGL(attn, dim3(512), dim3(256), 0, stream, qb, kb, vT, yb);
  hipLaunchKernelGGL(proj_gemm, dim3(8, 32), dim3(256), 0, stream, yb, WpT, b_proj, out);
}

// Round 8
// 189.872 us; speedup vs baseline: 1.6858x; 1.0671x over previous
//
#include <hip/hip_runtime.h>
#include <stdint.h>

typedef unsigned short u16;
typedef __attribute__((ext_vector_type(8))) short bf16x8;   // 8 bf16 (4 VGPRs) MFMA A/B frag
typedef __attribute__((ext_vector_type(4))) float f32x4;    // MFMA C/D frag
typedef __attribute__((ext_vector_type(4))) int   i32x4;
typedef __attribute__((ext_vector_type(4))) unsigned int u32x4;
typedef __attribute__((ext_vector_type(4))) unsigned short u16x4;

#define MFMA16(a, b, c) __builtin_amdgcn_mfma_f32_16x16x32_bf16((a), (b), (c), 0, 0, 0)

// ---- constants ----
#define BATCH 2
#define TSEQ  2048
#define CEMB  1024
#define NHEAD 16
#define DHEAD 64
#define BHTOT 32           // BATCH*NHEAD
#define MROWS 4096         // BATCH*TSEQ

__device__ __forceinline__ u16 bf16r(float f) {  // round-nearest-even fp32->bf16
  uint32_t u = __builtin_bit_cast(uint32_t, f);
  u += 0x7fffu + ((u >> 16) & 1u);
  return (u16)(u >> 16);
}

__device__ __forceinline__ float bf2f(short v) {
  return __builtin_bit_cast(float, ((uint32_t)(u16)v) << 16);
}

__device__ __forceinline__ bf16x8 scale8(bf16x8 a, float s) {
  bf16x8 r;
#pragma unroll
  for (int i = 0; i < 8; i++) r[i] = (short)bf16r(bf2f(a[i]) * s);
  return r;
}

__device__ __forceinline__ void gl2lds16(const void* g, void* l) {
  __builtin_amdgcn_global_load_lds(
      (const __attribute__((address_space(1))) uint32_t*)g,
      (__attribute__((address_space(3))) uint32_t*)l, 16, 0, 0);
}

// ---------------- prep kernels ----------------
__global__ void conv_x(const float* __restrict__ x, u16* __restrict__ xb, int n) {
  int i = (blockIdx.x * blockDim.x + threadIdx.x) * 4;
  if (i < n) {
    f32x4 v = *(const f32x4*)(x + i);
    u16x4 o;
    o[0] = bf16r(v[0]); o[1] = bf16r(v[1]); o[2] = bf16r(v[2]); o[3] = bf16r(v[3]);
    *(u16x4*)(xb + i) = o;
  }
}

// W[K][N] (fp32) -> WT[N][K] (bf16)
__global__ void transpose_w(const float* __restrict__ W, u16* __restrict__ WT, int K, int N) {
  __shared__ float t[32][33];
  int k0 = blockIdx.y * 32, n0 = blockIdx.x * 32;
  int tx = threadIdx.x & 31, ty = threadIdx.x >> 5;   // 32 x 8
  for (int i = 0; i < 4; i++)
    t[ty + i * 8][tx] = W[(size_t)(k0 + ty + i * 8) * N + n0 + tx];
  __syncthreads();
  for (int i = 0; i < 4; i++)
    WT[(size_t)(n0 + ty + i * 8) * K + k0 + tx] = bf16r(t[tx][ty + i * 8]);
}

// ---------------- GEMM mainloop (m97 structure: 128x128 tile, BK=32) ----------------
__device__ __forceinline__ void gemm_mainloop(const u16* __restrict__ A,
                                              const u16* __restrict__ Bt,
                                              int K, int m0, int n0,
                                              u16* AsU, u16* BsU, f32x4 acc[4][4]) {
  const int tid = threadIdx.x;
  const int wv = tid >> 6, ln = tid & 63;
  const int lr = ln & 15, lg = ln >> 4;
  const int wr = (wv >> 1) * 64, wc = (wv & 1) * 64;

  for (int mi = 0; mi < 4; mi++)
    for (int ni = 0; ni < 4; ni++) acc[mi][ni] = f32x4{0.f, 0.f, 0.f, 0.f};

  for (int k0 = 0; k0 < K; k0 += 32) {
    for (int p = 0; p < 2; ++p) {
      int chunk = p * 256 + tid;
      int row = chunk >> 2;
      int c8  = (chunk & 3) << 3;
      u16* abase = AsU + (size_t)(p * 256 + wv * 64) * 8;
      u16* bbase = BsU + (size_t)(p * 256 + wv * 64) * 8;
      gl2lds16(A  + (size_t)(m0 + row) * K + k0 + c8, abase);
      gl2lds16(Bt + (size_t)(n0 + row) * K + k0 + c8, bbase);
    }
    __syncthreads();
    bf16x8 af[4], bf[4];
    for (int mi = 0; mi < 4; mi++)
      af[mi] = *(const bf16x8*)&AsU[(size_t)(wr + mi * 16 + lr) * 32 + lg * 8];
    for (int ni = 0; ni < 4; ni++)
      bf[ni] = *(const bf16x8*)&BsU[(size_t)(wc + ni * 16 + lr) * 32 + lg * 8];
    for (int mi = 0; mi < 4; mi++)
      for (int ni = 0; ni < 4; ni++)
        acc[mi][ni] = MFMA16(af[mi], bf[ni], acc[mi][ni]);
    __syncthreads();
  }
}

// ---------------- QKV GEMM ----------------
__global__ __launch_bounds__(256, 2) void qkv_gemm(const u16* __restrict__ xb,
                                                   const u16* __restrict__ WaT,
                                                   const float* __restrict__ b_attn,
                                                   u16* __restrict__ qb, u16* __restrict__ kb,
                                                   u16* __restrict__ vT) {
  __shared__ u16 AsU[128 * 32];
  __shared__ u16 BsU[128 * 32];
  const int m0 = blockIdx.y * 128, n0 = blockIdx.x * 128;
  f32x4 acc[4][4];
  gemm_mainloop(xb, WaT, CEMB, m0, n0, AsU, BsU, acc);

  const int tid = threadIdx.x;
  const int wv = tid >> 6, ln = tid & 63, lr = ln & 15, lg = ln >> 4;
  const int wr = (wv >> 1) * 64, wc = (wv & 1) * 64;
  for (int mi = 0; mi < 4; mi++)
    for (int ni = 0; ni < 4; ni++) {
      int col = n0 + wc + ni * 16 + lr;               // 0..3071
      float bias = b_attn[col];
      int which = col >> 10;                          // 0=q 1=k 2=v
      int cl = col & 1023, h = cl >> 6, d = cl & 63;
      for (int j = 0; j < 4; j++) {
        int m = m0 + wr + mi * 16 + lg * 4 + j;       // 0..4095
        int b = m >> 11, t = m & 2047;
        u16 bv = bf16r(acc[mi][ni][j] + bias);
        size_t bh = (size_t)(b * NHEAD + h);
        if (which == 0)      qb[(bh * TSEQ + t) * DHEAD + d] = bv;
        else if (which == 1) kb[(bh * TSEQ + t) * DHEAD + d] = bv;
        else                 vT[(bh * DHEAD + d) * TSEQ + t] = bv;   // transposed store
      }
    }
}

// ---------------- flash attention v4 ----------------
// v3 post-mortem: grid 512 = 2 blocks/CU, LDS 55KB also caps at 2 -> 8 waves/CU,
// latency-bound. v4: QBLK=64 (4 waves x 16 q), grid 1024; drop Ps LDS -- P goes
// to PV B-frags via cvt+2-stage shfl_xor butterfly (lane algebra in comments).
// LDS 36864 -> 4 blocks/CU -> 16 waves/CU. Foursome qblk mapping {31-s, s,
// 23-s, 8+s}: every CU's 4 resident blocks sum to 66 tiles (uniform makespan).
__global__ __launch_bounds__(256, 4) void attn(const u16* __restrict__ qb,
                                               const u16* __restrict__ kb,
                                               const u16* __restrict__ vT,
                                               u16* __restrict__ yb) {
  const int flat = blockIdx.x;                  // 1024 blocks
  const int x = flat & 7;                       // XCD id (4 heads per XCD)
  const int l = flat >> 3;                      // 0..127 within XCD
  const int r = l & 31, a = l >> 5, rq = r & 7;
  const int bh = 4 * x + (r >> 3);
  const int qblk = (a == 0) ? 31 - rq : (a == 1) ? rq : (a == 2) ? 23 - rq : 8 + rq;

  const int tid = threadIdx.x, wv = tid >> 6, ln = tid & 63, lr = ln & 15, lg = ln >> 4;
  const int b1 = lg >> 1, b0 = lg & 1;

  __shared__ u16 Ks[2][64][72];       // K tile [k][d], dbuf, +8 pad
  __shared__ u16 Vs[2][64][72];       // V^T tile [d][k], dbuf, +8 pad

  const int wq0 = qblk * 64 + wv * 16;
  const float SCL = 0.125f * 1.44269504f;   // 1/sqrt(64) * log2(e)

  // Q fragments pre-scaled (B operand: lr = q-col, lg*8 = d-slice)
  bf16x8 qf0, qf1;
  {
    const u16* qrow = qb + ((size_t)bh * TSEQ + (wq0 + lr)) * DHEAD + lg * 8;
    qf0 = scale8(*(const bf16x8*)(qrow), SCL);
    qf1 = scale8(*(const bf16x8*)(qrow + 32), SCL);
  }

  f32x4 acc[4];
#pragma unroll
  for (int df = 0; df < 4; df++) acc[df] = f32x4{0.f, 0.f, 0.f, 0.f};
  float mrun = -1e30f, lrun = 0.f;

  const int ntiles = qblk + 1;
  const int srow = tid >> 3, sc8 = (tid & 7) << 3;   // staging: 8 lanes/row

  // prologue: tile 0 -> LDS buf0; issue tile 1 -> regs (rows always in-bounds)
  i32x4 kreg[2], vreg[2];
#pragma unroll
  for (int p = 0; p < 2; p++) {
    int row = p * 32 + srow;
    *(i32x4*)&Ks[0][row][sc8] = *(const i32x4*)(kb + ((size_t)bh * TSEQ + row) * DHEAD + sc8);
    *(i32x4*)&Vs[0][row][sc8] = *(const i32x4*)(vT + ((size_t)bh * DHEAD + row) * TSEQ + sc8);
  }
#pragma unroll
  for (int p = 0; p < 2; p++) {
    int row = p * 32 + srow;
    kreg[p] = *(const i32x4*)(kb + ((size_t)bh * TSEQ + 64 + row) * DHEAD + sc8);
    vreg[p] = *(const i32x4*)(vT + ((size_t)bh * DHEAD + row) * TSEQ + 64 + sc8);
  }

  int c = 0;
  for (int kt = 0; kt < ntiles; kt++) {
    const int kbase = kt * 64;
    __syncthreads();   // buf[c] staged; prior reads of buf[c^1] done

    // S^T = K Q^T on buf[c] : 8 MFMA  (s[st]: k-rows st*16+lg*4+j, q-col lr)
    f32x4 s[4];
#pragma unroll
    for (int st = 0; st < 4; st++) {
      bf16x8 kf0 = *(const bf16x8*)&Ks[c][st * 16 + lr][lg * 8];
      bf16x8 kf1 = *(const bf16x8*)&Ks[c][st * 16 + lr][32 + lg * 8];
      f32x4 z = f32x4{0.f, 0.f, 0.f, 0.f};
      z = MFMA16(kf0, qf0, z);
      z = MFMA16(kf1, qf1, z);
      s[st] = z;
    }

    // stage tile kt+1 into buf[c^1] (vmcnt wait hides under QK MFMAs)
    if (kt + 1 < ntiles) {
#pragma unroll
      for (int p = 0; p < 2; p++) {
        int row = p * 32 + srow;
        *(i32x4*)&Ks[c ^ 1][row][sc8] = kreg[p];
        *(i32x4*)&Vs[c ^ 1][row][sc8] = vreg[p];
      }
    }
    // issue prefetch of tile kt+2
    if (kt + 2 < ntiles) {
      const int nb = kbase + 128;
#pragma unroll
      for (int p = 0; p < 2; p++) {
        int row = p * 32 + srow;
        kreg[p] = *(const i32x4*)(kb + ((size_t)bh * TSEQ + nb + row) * DHEAD + sc8);
        vreg[p] = *(const i32x4*)(vT + ((size_t)bh * DHEAD + row) * TSEQ + nb + sc8);
      }
    }

    // ---- online softmax: lane owns q = wq0 + lr; 16 k-values in-lane ----
    float mt = -1e30f;
    if (kt == ntiles - 1) {              // only the last tile is diagonal
      const int qg = wq0 + lr;
#pragma unroll
      for (int st = 0; st < 4; st++)
#pragma unroll
        for (int j = 0; j < 4; j++) {
          int kg = kbase + st * 16 + lg * 4 + j;
          float v = (kg <= qg) ? s[st][j] : -1e30f;
          s[st][j] = v;
          mt = fmaxf(mt, v);
        }
    } else {
#pragma unroll
      for (int st = 0; st < 4; st++)
#pragma unroll
        for (int j = 0; j < 4; j++) mt = fmaxf(mt, s[st][j]);
    }
    mt = fmaxf(mt, __shfl_xor(mt, 16));
    mt = fmaxf(mt, __shfl_xor(mt, 32));
    if (!__all(mt <= mrun)) {            // T13: skip rescale when max stable
      float mnew = fmaxf(mrun, mt);
      float al = __builtin_amdgcn_exp2f(mrun - mnew);
#pragma unroll
      for (int df = 0; df < 4; df++)
#pragma unroll
        for (int j = 0; j < 4; j++) acc[df][j] *= al;
      lrun *= al;
      mrun = mnew;
    }
    float rs = 0.f;
#pragma unroll
    for (int st = 0; st < 4; st++)
#pragma unroll
      for (int j = 0; j < 4; j++) {
        float p = __builtin_amdgcn_exp2f(s[st][j] - mrun);
        s[st][j] = p;
        rs += p;
      }
    rs += __shfl_xor(rs, 16);
    rs += __shfl_xor(rs, 32);
    lrun += rs;

    // ---- P -> PV B-frags, in-register butterfly (replaces Ps LDS) ----
    // W[st][h] = packed bf16 pair (k = st*16+lg*4+2h, +1), q = lr.
    // Need: pf[ks].word[2p+h] = W[2ks+b1][h] from lane-group g = 2*b0+p.
    // Stage 1 (xor32): send st = b1^1, 2+b1^1; keep st = b1, 2+b1.
    // Stage 2 (xor16): own-kept crosses iff b0!=b1; partner-recv iff b0==b1.
    uint32_t W[4][2];
#pragma unroll
    for (int st = 0; st < 4; st++) {
      W[st][0] = (uint32_t)bf16r(s[st][0]) | ((uint32_t)bf16r(s[st][1]) << 16);
      W[st][1] = (uint32_t)bf16r(s[st][2]) | ((uint32_t)bf16r(s[st][3]) << 16);
    }
    uint32_t Ka[2], Kb[2], Xa[2], Xb[2];
#pragma unroll
    for (int h = 0; h < 2; h++) {
      uint32_t S1a = b1 ? W[0][h] : W[1][h];    // st = b1^1
      uint32_t S1b = b1 ? W[2][h] : W[3][h];    // st = 2+b1^1
      Xa[h] = __shfl_xor(S1a, 32);              // recv: partner-group W[b1]
      Xb[h] = __shfl_xor(S1b, 32);              // recv: partner-group W[2+b1]
      Ka[h] = b1 ? W[1][h] : W[0][h];           // keep: own W[b1]
      Kb[h] = b1 ? W[3][h] : W[2][h];           // keep: own W[2+b1]
    }
    const bool e = (b0 == b1);
    uint32_t Ta[2], Tb[2], Ra[2], Rb[2];
#pragma unroll
    for (int h = 0; h < 2; h++) {
      uint32_t Cah = e ? Xa[h] : Ka[h];
      uint32_t Cbh = e ? Xb[h] : Kb[h];
      Ta[h] = e ? Ka[h] : Xa[h];
      Tb[h] = e ? Kb[h] : Xb[h];
      Ra[h] = __shfl_xor(Cah, 16);
      Rb[h] = __shfl_xor(Cbh, 16);
    }
    // assemble: T has quartet p = b0, R has p = b0^1
    u32x4 w0, w1;
    w0[0] = b0 ? Ra[0] : Ta[0];  w0[1] = b0 ? Ra[1] : Ta[1];
    w0[2] = b0 ? Ta[0] : Ra[0];  w0[3] = b0 ? Ta[1] : Ra[1];
    w1[0] = b0 ? Rb[0] : Tb[0];  w1[1] = b0 ? Rb[1] : Tb[1];
    w1[2] = b0 ? Tb[0] : Rb[0];  w1[3] = b0 ? Tb[1] : Rb[1];
    bf16x8 pf0 = __builtin_bit_cast(bf16x8, w0);   // B-frag, k = lg*8..+7
    bf16x8 pf1 = __builtin_bit_cast(bf16x8, w1);   // B-frag, k = 32+lg*8..+7

    // y^T += V^T P on buf[c] : 8 MFMA
#pragma unroll
    for (int df = 0; df < 4; df++) {
      bf16x8 vf0 = *(const bf16x8*)&Vs[c][df * 16 + lr][lg * 8];
      bf16x8 vf1 = *(const bf16x8*)&Vs[c][df * 16 + lr][32 + lg * 8];
      acc[df] = MFMA16(vf0, pf0, acc[df]);
      acc[df] = MFMA16(vf1, pf1, acc[df]);
    }
    c ^= 1;
  }

  // epilogue: y = acc / l -> yb[b][t][h*64+d]
  const int b = bh >> 4, h = bh & 15;
  float inv = 1.f / lrun;
  int tg = wq0 + lr;
#pragma unroll
  for (int df = 0; df < 4; df++) {
    u16x4 o;
#pragma unroll
    for (int j = 0; j < 4; j++) o[j] = bf16r(acc[df][j] * inv);
    *(u16x4*)&yb[((size_t)b * TSEQ + tg) * CEMB + h * 64 + df * 16 + lg * 4] = o;
  }
}

// ---------------- proj GEMM ----------------
__global__ __launch_bounds__(256, 2) void proj_gemm(const u16* __restrict__ yb,
                                                    const u16* __restrict__ WpT,
                                                    const float* __restrict__ b_proj,
                                                    float* __restrict__ out) {
  __shared__ u16 AsU[128 * 32];
  __shared__ u16 BsU[128 * 32];
  const int m0 = blockIdx.y * 128, n0 = blockIdx.x * 128;
  f32x4 acc[4][4];
  gemm_mainloop(yb, WpT, CEMB, m0, n0, AsU, BsU, acc);

  const int tid = threadIdx.x;
  const int wv = tid >> 6, ln = tid & 63, lr = ln & 15, lg = ln >> 4;
  const int wr = (wv >> 1) * 64, wc = (wv & 1) * 64;
  for (int mi = 0; mi < 4; mi++)
    for (int ni = 0; ni < 4; ni++) {
      int col = n0 + wc + ni * 16 + lr;
      float bias = b_proj[col];
      for (int j = 0; j < 4; j++) {
        int m = m0 + wr + mi * 16 + lg * 4 + j;
        out[(size_t)m * CEMB + col] = acc[mi][ni][j] + bias;
      }
    }
}

// ---------------- launch ----------------
extern "C" void kernel_launch(void* const* d_in, const int* in_sizes, int n_in,
                              void* d_out, int out_size, void* d_ws, size_t ws_size,
                              hipStream_t stream) {
  const float* x      = (const float*)d_in[0];
  const float* W_attn = (const float*)d_in[1];
  const float* b_attn = (const float*)d_in[2];
  const float* W_proj = (const float*)d_in[3];
  const float* b_proj = (const float*)d_in[4];
  float* out = (float*)d_out;
  char* ws = (char*)d_ws;

  u16* xb  = (u16*)(ws);                 //  8 MB  [4096][1024] bf16
  u16* WaT = (u16*)(ws + 8388608);       //  6 MB  [3072][1024]
  u16* WpT = (u16*)(ws + 14680064);      //  2 MB  [1024][1024]
  u16* qb  = (u16*)(ws + 16777216);      //  8 MB  [BH][T][D]
  u16* kb  = (u16*)(ws + 25165824);      //  8 MB  [BH][T][D]
  u16* vT  = (u16*)(ws + 33554432);      //  8 MB  [BH][D][T]
  u16* yb  = (u16*)(ws + 41943040);      //  8 MB  [B][T][C]

  hipLaunchKernelGGL(conv_x, dim3(4096), dim3(256), 0, stream, x, xb, MROWS * CEMB);
  hipLaunchKernelGGL(transpose_w, dim3(96, 32), dim3(256), 0, stream, W_attn, WaT, 1024, 3072);
  hipLaunchKernelGGL(transpose_w, dim3(32, 32), dim3(256), 0, stream, W_proj, WpT, 1024, 1024);
  hipLaunchKernelGGL(qkv_gemm, dim3(24, 32), dim3(256), 0, stream, xb, WaT, b_attn, qb, kb, vT);
  hipLaunchKernelGGL(attn, dim3(1024), dim3(256), 0, stream, qb, kb, vT, yb);
  hipLaunchKernelGGL(proj_gemm, dim3(8, 32), dim3(256), 0, stream, yb, WpT, b_proj, out);
}

// Round 9
// 183.229 us; speedup vs baseline: 1.7469x; 1.0363x over previous
//
#include <hip/hip_runtime.h>
#include <stdint.h>

typedef unsigned short u16;
typedef __attribute__((ext_vector_type(8))) short bf16x8;   // 8 bf16 (4 VGPRs) MFMA A/B frag
typedef __attribute__((ext_vector_type(4))) float f32x4;    // MFMA C/D frag
typedef __attribute__((ext_vector_type(4))) int   i32x4;
typedef __attribute__((ext_vector_type(4))) unsigned int u32x4;
typedef __attribute__((ext_vector_type(4))) unsigned short u16x4;

#define MFMA16(a, b, c) __builtin_amdgcn_mfma_f32_16x16x32_bf16((a), (b), (c), 0, 0, 0)

// ---- constants ----
#define BATCH 2
#define TSEQ  2048
#define CEMB  1024
#define NHEAD 16
#define DHEAD 64
#define BHTOT 32           // BATCH*NHEAD
#define MROWS 4096         // BATCH*TSEQ

__device__ __forceinline__ u16 bf16r(float f) {  // round-nearest-even fp32->bf16
  uint32_t u = __builtin_bit_cast(uint32_t, f);
  u += 0x7fffu + ((u >> 16) & 1u);
  return (u16)(u >> 16);
}

__device__ __forceinline__ uint32_t cvt_pk_bf16(float lo, float hi) {
  uint32_t r;  // packed {hi:bf16(hi), lo:bf16(lo)} in 1 VALU op (no builtin on gfx950)
  asm("v_cvt_pk_bf16_f32 %0, %1, %2" : "=v"(r) : "v"(lo), "v"(hi));
  return r;
}

__device__ __forceinline__ float bf2f(short v) {
  return __builtin_bit_cast(float, ((uint32_t)(u16)v) << 16);
}

__device__ __forceinline__ bf16x8 scale8(bf16x8 a, float s) {
  bf16x8 r;
#pragma unroll
  for (int i = 0; i < 8; i++) r[i] = (short)bf16r(bf2f(a[i]) * s);
  return r;
}

__device__ __forceinline__ void gl2lds16(const void* g, void* l) {
  __builtin_amdgcn_global_load_lds(
      (const __attribute__((address_space(1))) uint32_t*)g,
      (__attribute__((address_space(3))) uint32_t*)l, 16, 0, 0);
}

// ---------------- fused prep: conv_x (bid<4096) | W_attn^T (4096..7168) | W_proj^T ----------------
__global__ void prep(const float* __restrict__ x, u16* __restrict__ xb,
                     const float* __restrict__ W_attn, u16* __restrict__ WaT,
                     const float* __restrict__ W_proj, u16* __restrict__ WpT) {
  __shared__ float t[32][33];
  const int bid = blockIdx.x;
  if (bid < 4096) {                     // x fp32 -> bf16, 4 elems/thread
    int i = (bid * 256 + threadIdx.x) * 4;
    f32x4 v = *(const f32x4*)(x + i);
    u16x4 o;
    o[0] = bf16r(v[0]); o[1] = bf16r(v[1]); o[2] = bf16r(v[2]); o[3] = bf16r(v[3]);
    *(u16x4*)(xb + i) = o;
    return;
  }
  const float* W; u16* WT; int K, N, idx;
  if (bid < 7168) { W = W_attn; WT = WaT; K = 1024; N = 3072; idx = bid - 4096;
                    idx = (idx % 96) | ((idx / 96) << 16); }
  else            { W = W_proj; WT = WpT; K = 1024; N = 1024; idx = bid - 7168;
                    idx = (idx % 32) | ((idx / 32) << 16); }
  int n0 = (idx & 0xffff) * 32, k0 = (idx >> 16) * 32;
  int tx = threadIdx.x & 31, ty = threadIdx.x >> 5;   // 32 x 8
  for (int i = 0; i < 4; i++)
    t[ty + i * 8][tx] = W[(size_t)(k0 + ty + i * 8) * N + n0 + tx];
  __syncthreads();
  for (int i = 0; i < 4; i++)
    WT[(size_t)(n0 + ty + i * 8) * K + k0 + tx] = bf16r(t[tx][ty + i * 8]);
}

// ---------------- GEMM mainloop (m97 structure: 128x128 tile, BK=32) ----------------
__device__ __forceinline__ void gemm_mainloop(const u16* __restrict__ A,
                                              const u16* __restrict__ Bt,
                                              int K, int m0, int n0,
                                              u16* AsU, u16* BsU, f32x4 acc[4][4]) {
  const int tid = threadIdx.x;
  const int wv = tid >> 6, ln = tid & 63;
  const int lr = ln & 15, lg = ln >> 4;
  const int wr = (wv >> 1) * 64, wc = (wv & 1) * 64;

  for (int mi = 0; mi < 4; mi++)
    for (int ni = 0; ni < 4; ni++) acc[mi][ni] = f32x4{0.f, 0.f, 0.f, 0.f};

  for (int k0 = 0; k0 < K; k0 += 32) {
    for (int p = 0; p < 2; ++p) {
      int chunk = p * 256 + tid;
      int row = chunk >> 2;
      int c8  = (chunk & 3) << 3;
      u16* abase = AsU + (size_t)(p * 256 + wv * 64) * 8;
      u16* bbase = BsU + (size_t)(p * 256 + wv * 64) * 8;
      gl2lds16(A  + (size_t)(m0 + row) * K + k0 + c8, abase);
      gl2lds16(Bt + (size_t)(n0 + row) * K + k0 + c8, bbase);
    }
    __syncthreads();
    bf16x8 af[4], bf[4];
    for (int mi = 0; mi < 4; mi++)
      af[mi] = *(const bf16x8*)&AsU[(size_t)(wr + mi * 16 + lr) * 32 + lg * 8];
    for (int ni = 0; ni < 4; ni++)
      bf[ni] = *(const bf16x8*)&BsU[(size_t)(wc + ni * 16 + lr) * 32 + lg * 8];
    for (int mi = 0; mi < 4; mi++)
      for (int ni = 0; ni < 4; ni++)
        acc[mi][ni] = MFMA16(af[mi], bf[ni], acc[mi][ni]);
    __syncthreads();
  }
}

// ---------------- QKV GEMM ----------------
__global__ __launch_bounds__(256, 2) void qkv_gemm(const u16* __restrict__ xb,
                                                   const u16* __restrict__ WaT,
                                                   const float* __restrict__ b_attn,
                                                   u16* __restrict__ qb, u16* __restrict__ kb,
                                                   u16* __restrict__ vT) {
  __shared__ u16 AsU[128 * 32];
  __shared__ u16 BsU[128 * 32];
  const int m0 = blockIdx.y * 128, n0 = blockIdx.x * 128;
  f32x4 acc[4][4];
  gemm_mainloop(xb, WaT, CEMB, m0, n0, AsU, BsU, acc);

  const int tid = threadIdx.x;
  const int wv = tid >> 6, ln = tid & 63, lr = ln & 15, lg = ln >> 4;
  const int wr = (wv >> 1) * 64, wc = (wv & 1) * 64;
  for (int mi = 0; mi < 4; mi++)
    for (int ni = 0; ni < 4; ni++) {
      int col = n0 + wc + ni * 16 + lr;               // 0..3071
      float bias = b_attn[col];
      int which = col >> 10;                          // 0=q 1=k 2=v
      int cl = col & 1023, h = cl >> 6, d = cl & 63;
      for (int j = 0; j < 4; j++) {
        int m = m0 + wr + mi * 16 + lg * 4 + j;       // 0..4095
        int b = m >> 11, t = m & 2047;
        u16 bv = bf16r(acc[mi][ni][j] + bias);
        size_t bh = (size_t)(b * NHEAD + h);
        if (which == 0)      qb[(bh * TSEQ + t) * DHEAD + d] = bv;
        else if (which == 1) kb[(bh * TSEQ + t) * DHEAD + d] = bv;
        else                 vT[(bh * DHEAD + d) * TSEQ + t] = bv;   // transposed store
      }
    }
}

// ---------------- flash attention v4.1 ----------------
// v4 post-mortem: 45.8us, VALU 47% busiest pipe; ~64 VALU/tile/lane was manual
// bf16 rounding of P. v4.1: pack P via v_cvt_pk_bf16_f32 (8 ops). Rest identical.
__global__ __launch_bounds__(256, 4) void attn(const u16* __restrict__ qb,
                                               const u16* __restrict__ kb,
                                               const u16* __restrict__ vT,
                                               u16* __restrict__ yb) {
  const int flat = blockIdx.x;                  // 1024 blocks
  const int x = flat & 7;                       // XCD id (4 heads per XCD)
  const int l = flat >> 3;                      // 0..127 within XCD
  const int r = l & 31, a = l >> 5, rq = r & 7;
  const int bh = 4 * x + (r >> 3);
  const int qblk = (a == 0) ? 31 - rq : (a == 1) ? rq : (a == 2) ? 23 - rq : 8 + rq;

  const int tid = threadIdx.x, wv = tid >> 6, ln = tid & 63, lr = ln & 15, lg = ln >> 4;
  const int b1 = lg >> 1, b0 = lg & 1;

  __shared__ u16 Ks[2][64][72];       // K tile [k][d], dbuf, +8 pad
  __shared__ u16 Vs[2][64][72];       // V^T tile [d][k], dbuf, +8 pad

  const int wq0 = qblk * 64 + wv * 16;
  const float SCL = 0.125f * 1.44269504f;   // 1/sqrt(64) * log2(e)

  // Q fragments pre-scaled (B operand: lr = q-col, lg*8 = d-slice)
  bf16x8 qf0, qf1;
  {
    const u16* qrow = qb + ((size_t)bh * TSEQ + (wq0 + lr)) * DHEAD + lg * 8;
    qf0 = scale8(*(const bf16x8*)(qrow), SCL);
    qf1 = scale8(*(const bf16x8*)(qrow + 32), SCL);
  }

  f32x4 acc[4];
#pragma unroll
  for (int df = 0; df < 4; df++) acc[df] = f32x4{0.f, 0.f, 0.f, 0.f};
  float mrun = -1e30f, lrun = 0.f;

  const int ntiles = qblk + 1;
  const int srow = tid >> 3, sc8 = (tid & 7) << 3;   // staging: 8 lanes/row

  // prologue: tile 0 -> LDS buf0; issue tile 1 -> regs
  i32x4 kreg[2], vreg[2];
#pragma unroll
  for (int p = 0; p < 2; p++) {
    int row = p * 32 + srow;
    *(i32x4*)&Ks[0][row][sc8] = *(const i32x4*)(kb + ((size_t)bh * TSEQ + row) * DHEAD + sc8);
    *(i32x4*)&Vs[0][row][sc8] = *(const i32x4*)(vT + ((size_t)bh * DHEAD + row) * TSEQ + sc8);
  }
#pragma unroll
  for (int p = 0; p < 2; p++) {
    int row = p * 32 + srow;
    kreg[p] = *(const i32x4*)(kb + ((size_t)bh * TSEQ + 64 + row) * DHEAD + sc8);
    vreg[p] = *(const i32x4*)(vT + ((size_t)bh * DHEAD + row) * TSEQ + 64 + sc8);
  }

  int c = 0;
  for (int kt = 0; kt < ntiles; kt++) {
    const int kbase = kt * 64;
    __syncthreads();   // buf[c] staged; prior reads of buf[c^1] done

    // S^T = K Q^T on buf[c] : 8 MFMA  (s[st]: k-rows st*16+lg*4+j, q-col lr)
    f32x4 s[4];
#pragma unroll
    for (int st = 0; st < 4; st++) {
      bf16x8 kf0 = *(const bf16x8*)&Ks[c][st * 16 + lr][lg * 8];
      bf16x8 kf1 = *(const bf16x8*)&Ks[c][st * 16 + lr][32 + lg * 8];
      f32x4 z = f32x4{0.f, 0.f, 0.f, 0.f};
      z = MFMA16(kf0, qf0, z);
      z = MFMA16(kf1, qf1, z);
      s[st] = z;
    }

    // stage tile kt+1 into buf[c^1] (vmcnt wait hides under QK MFMAs)
    if (kt + 1 < ntiles) {
#pragma unroll
      for (int p = 0; p < 2; p++) {
        int row = p * 32 + srow;
        *(i32x4*)&Ks[c ^ 1][row][sc8] = kreg[p];
        *(i32x4*)&Vs[c ^ 1][row][sc8] = vreg[p];
      }
    }
    // issue prefetch of tile kt+2
    if (kt + 2 < ntiles) {
      const int nb = kbase + 128;
#pragma unroll
      for (int p = 0; p < 2; p++) {
        int row = p * 32 + srow;
        kreg[p] = *(const i32x4*)(kb + ((size_t)bh * TSEQ + nb + row) * DHEAD + sc8);
        vreg[p] = *(const i32x4*)(vT + ((size_t)bh * DHEAD + row) * TSEQ + nb + sc8);
      }
    }

    // ---- online softmax: lane owns q = wq0 + lr; 16 k-values in-lane ----
    float mt = -1e30f;
    if (kt == ntiles - 1) {              // only the last tile is diagonal
      const int qg = wq0 + lr;
#pragma unroll
      for (int st = 0; st < 4; st++)
#pragma unroll
        for (int j = 0; j < 4; j++) {
          int kg = kbase + st * 16 + lg * 4 + j;
          float v = (kg <= qg) ? s[st][j] : -1e30f;
          s[st][j] = v;
          mt = fmaxf(mt, v);
        }
    } else {
#pragma unroll
      for (int st = 0; st < 4; st++)
#pragma unroll
        for (int j = 0; j < 4; j++) mt = fmaxf(mt, s[st][j]);
    }
    mt = fmaxf(mt, __shfl_xor(mt, 16));
    mt = fmaxf(mt, __shfl_xor(mt, 32));
    if (!__all(mt <= mrun)) {            // T13: skip rescale when max stable
      float mnew = fmaxf(mrun, mt);
      float al = __builtin_amdgcn_exp2f(mrun - mnew);
#pragma unroll
      for (int df = 0; df < 4; df++)
#pragma unroll
        for (int j = 0; j < 4; j++) acc[df][j] *= al;
      lrun *= al;
      mrun = mnew;
    }
    float rs = 0.f;
#pragma unroll
    for (int st = 0; st < 4; st++)
#pragma unroll
      for (int j = 0; j < 4; j++) {
        float p = __builtin_amdgcn_exp2f(s[st][j] - mrun);
        s[st][j] = p;
        rs += p;
      }
    rs += __shfl_xor(rs, 16);
    rs += __shfl_xor(rs, 32);
    lrun += rs;

    // ---- P -> PV B-frags, in-register butterfly (replaces Ps LDS) ----
    // W[st][h] = packed bf16 pair (k = st*16+lg*4+2h, +1), q = lr.
    // Need: pf[ks].word[2p+h] = W[2ks+b1][h] from lane-group g = 2*b0+p.
    // Stage 1 (xor32): send st = b1^1, 2+b1^1; keep st = b1, 2+b1.
    // Stage 2 (xor16): own-kept crosses iff b0!=b1; partner-recv iff b0==b1.
    uint32_t W[4][2];
#pragma unroll
    for (int st = 0; st < 4; st++) {
      W[st][0] = cvt_pk_bf16(s[st][0], s[st][1]);
      W[st][1] = cvt_pk_bf16(s[st][2], s[st][3]);
    }
    uint32_t Ka[2], Kb[2], Xa[2], Xb[2];
#pragma unroll
    for (int h = 0; h < 2; h++) {
      uint32_t S1a = b1 ? W[0][h] : W[1][h];    // st = b1^1
      uint32_t S1b = b1 ? W[2][h] : W[3][h];    // st = 2+b1^1
      Xa[h] = __shfl_xor(S1a, 32);              // recv: partner-group W[b1]
      Xb[h] = __shfl_xor(S1b, 32);              // recv: partner-group W[2+b1]
      Ka[h] = b1 ? W[1][h] : W[0][h];           // keep: own W[b1]
      Kb[h] = b1 ? W[3][h] : W[2][h];           // keep: own W[2+b1]
    }
    const bool e = (b0 == b1);
    uint32_t Ta[2], Tb[2], Ra[2], Rb[2];
#pragma unroll
    for (int h = 0; h < 2; h++) {
      uint32_t Cah = e ? Xa[h] : Ka[h];
      uint32_t Cbh = e ? Xb[h] : Kb[h];
      Ta[h] = e ? Ka[h] : Xa[h];
      Tb[h] = e ? Kb[h] : Xb[h];
      Ra[h] = __shfl_xor(Cah, 16);
      Rb[h] = __shfl_xor(Cbh, 16);
    }
    // assemble: T has quartet p = b0, R has p = b0^1
    u32x4 w0, w1;
    w0[0] = b0 ? Ra[0] : Ta[0];  w0[1] = b0 ? Ra[1] : Ta[1];
    w0[2] = b0 ? Ta[0] : Ra[0];  w0[3] = b0 ? Ta[1] : Ra[1];
    w1[0] = b0 ? Rb[0] : Tb[0];  w1[1] = b0 ? Rb[1] : Tb[1];
    w1[2] = b0 ? Tb[0] : Rb[0];  w1[3] = b0 ? Tb[1] : Rb[1];
    bf16x8 pf0 = __builtin_bit_cast(bf16x8, w0);   // B-frag, k = lg*8..+7
    bf16x8 pf1 = __builtin_bit_cast(bf16x8, w1);   // B-frag, k = 32+lg*8..+7

    // y^T += V^T P on buf[c] : 8 MFMA
#pragma unroll
    for (int df = 0; df < 4; df++) {
      bf16x8 vf0 = *(const bf16x8*)&Vs[c][df * 16 + lr][lg * 8];
      bf16x8 vf1 = *(const bf16x8*)&Vs[c][df * 16 + lr][32 + lg * 8];
      acc[df] = MFMA16(vf0, pf0, acc[df]);
      acc[df] = MFMA16(vf1, pf1, acc[df]);
    }
    c ^= 1;
  }

  // epilogue: y = acc / l -> yb[b][t][h*64+d]
  const int b = bh >> 4, h = bh & 15;
  float inv = 1.f / lrun;
  int tg = wq0 + lr;
#pragma unroll
  for (int df = 0; df < 4; df++) {
    u16x4 o;
#pragma unroll
    for (int j = 0; j < 4; j++) o[j] = bf16r(acc[df][j] * inv);
    *(u16x4*)&yb[((size_t)b * TSEQ + tg) * CEMB + h * 64 + df * 16 + lg * 4] = o;
  }
}

// ---------------- proj GEMM ----------------
__global__ __launch_bounds__(256, 2) void proj_gemm(const u16* __restrict__ yb,
                                                    const u16* __restrict__ WpT,
                                                    const float* __restrict__ b_proj,
                                                    float* __restrict__ out) {
  __shared__ u16 AsU[128 * 32];
  __shared__ u16 BsU[128 * 32];
  const int m0 = blockIdx.y * 128, n0 = blockIdx.x * 128;
  f32x4 acc[4][4];
  gemm_mainloop(yb, WpT, CEMB, m0, n0, AsU, BsU, acc);

  const int tid = threadIdx.x;
  const int wv = tid >> 6, ln = tid & 63, lr = ln & 15, lg = ln >> 4;
  const int wr = (wv >> 1) * 64, wc = (wv & 1) * 64;
  for (int mi = 0; mi < 4; mi++)
    for (int ni = 0; ni < 4; ni++) {
      int col = n0 + wc + ni * 16 + lr;
      float bias = b_proj[col];
      for (int j = 0; j < 4; j++) {
        int m = m0 + wr + mi * 16 + lg * 4 + j;
        out[(size_t)m * CEMB + col] = acc[mi][ni][j] + bias;
      }
    }
}

// ---------------- launch ----------------
extern "C" void kernel_launch(void* const* d_in, const int* in_sizes, int n_in,
                              void* d_out, int out_size, void* d_ws, size_t ws_size,
                              hipStream_t stream) {
  const float* x      = (const float*)d_in[0];
  const float* W_attn = (const float*)d_in[1];
  const float* b_attn = (const float*)d_in[2];
  const float* W_proj = (const float*)d_in[3];
  const float* b_proj = (const float*)d_in[4];
  float* out = (float*)d_out;
  char* ws = (char*)d_ws;

  u16* xb  = (u16*)(ws);                 //  8 MB  [4096][1024] bf16
  u16* WaT = (u16*)(ws + 8388608);       //  6 MB  [3072][1024]
  u16* WpT = (u16*)(ws + 14680064);      //  2 MB  [1024][1024]
  u16* qb  = (u16*)(ws + 16777216);      //  8 MB  [BH][T][D]
  u16* kb  = (u16*)(ws + 25165824);      //  8 MB  [BH][T][D]
  u16* vT  = (u16*)(ws + 33554432);      //  8 MB  [BH][D][T]
  u16* yb  = (u16*)(ws + 41943040);      //  8 MB  [B][T][C]

  hipLaunchKernelGGL(prep, dim3(8192), dim3(256), 0, stream, x, xb, W_attn, WaT, W_proj, WpT);
  hipLaunchKernelGGL(qkv_gemm, dim3(24, 32), dim3(256), 0, stream, xb, WaT, b_attn, qb, kb, vT);
  hipLaunchKernelGGL(attn, dim3(1024), dim3(256), 0, stream, qb, kb, vT, yb);
  hipLaunchKernelGGL(proj_gemm, dim3(8, 32), dim3(256), 0, stream, yb, WpT, b_proj, out);
}

// Round 13
// 181.424 us; speedup vs baseline: 1.7643x; 1.0100x over previous
//
#include <hip/hip_runtime.h>
#include <stdint.h>

typedef unsigned short u16;
typedef __attribute__((ext_vector_type(8))) short bf16x8;   // 8 bf16 (4 VGPRs) MFMA A/B frag
typedef __attribute__((ext_vector_type(4))) float f32x4;    // MFMA C/D frag
typedef __attribute__((ext_vector_type(4))) int   i32x4;
typedef __attribute__((ext_vector_type(4))) unsigned int u32x4;
typedef __attribute__((ext_vector_type(4))) unsigned short u16x4;

#define MFMA16(a, b, c) __builtin_amdgcn_mfma_f32_16x16x32_bf16((a), (b), (c), 0, 0, 0)

// ---- constants ----
#define BATCH 2
#define TSEQ  2048
#define CEMB  1024
#define NHEAD 16
#define DHEAD 64
#define BHTOT 32           // BATCH*NHEAD
#define MROWS 4096         // BATCH*TSEQ

__device__ __forceinline__ u16 bf16r(float f) {  // round-nearest-even fp32->bf16
  uint32_t u = __builtin_bit_cast(uint32_t, f);
  u += 0x7fffu + ((u >> 16) & 1u);
  return (u16)(u >> 16);
}

__device__ __forceinline__ uint32_t cvt_pk_bf16(float lo, float hi) {
  uint32_t r;  // packed {hi:bf16(hi), lo:bf16(lo)} in 1 VALU op (no builtin on gfx950)
  asm("v_cvt_pk_bf16_f32 %0, %1, %2" : "=v"(r) : "v"(lo), "v"(hi));
  return r;
}

__device__ __forceinline__ float bf2f(short v) {
  return __builtin_bit_cast(float, ((uint32_t)(u16)v) << 16);
}

__device__ __forceinline__ bf16x8 scale8(bf16x8 a, float s) {
  bf16x8 r;
#pragma unroll
  for (int i = 0; i < 8; i++) r[i] = (short)bf16r(bf2f(a[i]) * s);
  return r;
}

__device__ __forceinline__ void gl2lds16(const void* g, void* l) {
  __builtin_amdgcn_global_load_lds(
      (const __attribute__((address_space(1))) uint32_t*)g,
      (__attribute__((address_space(3))) uint32_t*)l, 16, 0, 0);
}

// ---------------- fused prep: conv_x (bid<4096) | W_attn^T (4096..7168) | W_proj^T ----------------
__global__ void prep(const float* __restrict__ x, u16* __restrict__ xb,
                     const float* __restrict__ W_attn, u16* __restrict__ WaT,
                     const float* __restrict__ W_proj, u16* __restrict__ WpT) {
  __shared__ float t[32][33];
  const int bid = blockIdx.x;
  if (bid < 4096) {                     // x fp32 -> bf16, 4 elems/thread
    int i = (bid * 256 + threadIdx.x) * 4;
    f32x4 v = *(const f32x4*)(x + i);
    u16x4 o;
    o[0] = bf16r(v[0]); o[1] = bf16r(v[1]); o[2] = bf16r(v[2]); o[3] = bf16r(v[3]);
    *(u16x4*)(xb + i) = o;
    return;
  }
  const float* W; u16* WT; int K, N, idx;
  if (bid < 7168) { W = W_attn; WT = WaT; K = 1024; N = 3072; idx = bid - 4096;
                    idx = (idx % 96) | ((idx / 96) << 16); }
  else            { W = W_proj; WT = WpT; K = 1024; N = 1024; idx = bid - 7168;
                    idx = (idx % 32) | ((idx / 32) << 16); }
  int n0 = (idx & 0xffff) * 32, k0 = (idx >> 16) * 32;
  int tx = threadIdx.x & 31, ty = threadIdx.x >> 5;   // 32 x 8
  for (int i = 0; i < 4; i++)
    t[ty + i * 8][tx] = W[(size_t)(k0 + ty + i * 8) * N + n0 + tx];
  __syncthreads();
  for (int i = 0; i < 4; i++)
    WT[(size_t)(n0 + ty + i * 8) * K + k0 + tx] = bf16r(t[tx][ty + i * 8]);
}

// ---------------- GEMM mainloop v2: 2-phase double-buffered (T3-minimum) ----------------
// 128x128 tile, BK=32, LDS 2x(A,B) = 32 KB. Per K-step: issue STAGE(t+1) into
// buf^1 FIRST, then ds_read+16 MFMA on buf, then ONE barrier (its vmcnt(0)
// drain now waits on loads issued a full compute-phase earlier -> latency
// hidden in-wave, not just across waves). Replaces the 1-phase 2-barrier loop
// (stage -> drain-immediately -> compute -> barrier) measured at MfmaUtil 21%.
__device__ __forceinline__ void gemm_mainloop(const u16* __restrict__ A,
                                              const u16* __restrict__ Bt,
                                              int K, int m0, int n0,
                                              u16* AsU, u16* BsU, f32x4 acc[4][4]) {
  const int tid = threadIdx.x;
  const int wv = tid >> 6, ln = tid & 63;
  const int lr = ln & 15, lg = ln >> 4;
  const int wr = (wv >> 1) * 64, wc = (wv & 1) * 64;

  for (int mi = 0; mi < 4; mi++)
    for (int ni = 0; ni < 4; ni++) acc[mi][ni] = f32x4{0.f, 0.f, 0.f, 0.f};

  auto stage = [&](int buf, int k0) {
#pragma unroll
    for (int p = 0; p < 2; ++p) {
      int chunk = p * 256 + tid;
      int row = chunk >> 2;
      int c8  = (chunk & 3) << 3;
      u16* abase = AsU + buf * 4096 + (size_t)(p * 256 + wv * 64) * 8;
      u16* bbase = BsU + buf * 4096 + (size_t)(p * 256 + wv * 64) * 8;
      gl2lds16(A  + (size_t)(m0 + row) * K + k0 + c8, abase);
      gl2lds16(Bt + (size_t)(n0 + row) * K + k0 + c8, bbase);
    }
  };

  stage(0, 0);
  __syncthreads();                       // drain stage-0
  const int nt = K / 32;
  int cur = 0;
  for (int t = 0; t < nt; ++t) {
    if (t + 1 < nt) stage(cur ^ 1, (t + 1) * 32);   // issue-early (async)
    const u16* Ab = AsU + cur * 4096;
    const u16* Bb = BsU + cur * 4096;
    bf16x8 af[4], bf[4];
    for (int mi = 0; mi < 4; mi++)
      af[mi] = *(const bf16x8*)&Ab[(size_t)(wr + mi * 16 + lr) * 32 + lg * 8];
    for (int ni = 0; ni < 4; ni++)
      bf[ni] = *(const bf16x8*)&Bb[(size_t)(wc + ni * 16 + lr) * 32 + lg * 8];
    for (int mi = 0; mi < 4; mi++)
      for (int ni = 0; ni < 4; ni++)
        acc[mi][ni] = MFMA16(af[mi], bf[ni], acc[mi][ni]);
    __syncthreads();                     // one barrier/step: drains stage(t+1)
    cur ^= 1;
  }
}

// ---------------- QKV GEMM ----------------
__global__ __launch_bounds__(256, 2) void qkv_gemm(const u16* __restrict__ xb,
                                                   const u16* __restrict__ WaT,
                                                   const float* __restrict__ b_attn,
                                                   u16* __restrict__ qb, u16* __restrict__ kb,
                                                   u16* __restrict__ vT) {
  __shared__ u16 AsU[2 * 128 * 32];
  __shared__ u16 BsU[2 * 128 * 32];
  const int m0 = blockIdx.y * 128, n0 = blockIdx.x * 128;
  f32x4 acc[4][4];
  gemm_mainloop(xb, WaT, CEMB, m0, n0, AsU, BsU, acc);

  const int tid = threadIdx.x;
  const int wv = tid >> 6, ln = tid & 63, lr = ln & 15, lg = ln >> 4;
  const int wr = (wv >> 1) * 64, wc = (wv & 1) * 64;
  for (int mi = 0; mi < 4; mi++)
    for (int ni = 0; ni < 4; ni++) {
      int col = n0 + wc + ni * 16 + lr;               // 0..3071
      float bias = b_attn[col];
      int which = col >> 10;                          // 0=q 1=k 2=v (wave-uniform per ni)
      int cl = col & 1023, h = cl >> 6, d = cl & 63;
      int mbase = m0 + wr + mi * 16 + lg * 4;         // 4 consecutive m (same b)
      int b = mbase >> 11, t = mbase & 2047;
      size_t bh = (size_t)(b * NHEAD + h);
      if (which == 2) {                               // vT: t-contiguous -> u16x4
        u16x4 o;
        for (int j = 0; j < 4; j++) o[j] = bf16r(acc[mi][ni][j] + bias);
        *(u16x4*)&vT[(bh * DHEAD + d) * TSEQ + t] = o;
      } else {
        u16* dst = (which == 0) ? qb : kb;
        for (int j = 0; j < 4; j++)
          dst[(bh * TSEQ + t + j) * DHEAD + d] = bf16r(acc[mi][ni][j] + bias);
      }
    }
}

// ---------------- flash attention v4.1 (unchanged from round 9) ----------------
__global__ __launch_bounds__(256, 4) void attn(const u16* __restrict__ qb,
                                               const u16* __restrict__ kb,
                                               const u16* __restrict__ vT,
                                               u16* __restrict__ yb) {
  const int flat = blockIdx.x;                  // 1024 blocks
  const int x = flat & 7;                       // XCD id (4 heads per XCD)
  const int l = flat >> 3;                      // 0..127 within XCD
  const int r = l & 31, a = l >> 5, rq = r & 7;
  const int bh = 4 * x + (r >> 3);
  const int qblk = (a == 0) ? 31 - rq : (a == 1) ? rq : (a == 2) ? 23 - rq : 8 + rq;

  const int tid = threadIdx.x, wv = tid >> 6, ln = tid & 63, lr = ln & 15, lg = ln >> 4;
  const int b1 = lg >> 1, b0 = lg & 1;

  __shared__ u16 Ks[2][64][72];       // K tile [k][d], dbuf, +8 pad
  __shared__ u16 Vs[2][64][72];       // V^T tile [d][k], dbuf, +8 pad

  const int wq0 = qblk * 64 + wv * 16;
  const float SCL = 0.125f * 1.44269504f;   // 1/sqrt(64) * log2(e)

  // Q fragments pre-scaled (B operand: lr = q-col, lg*8 = d-slice)
  bf16x8 qf0, qf1;
  {
    const u16* qrow = qb + ((size_t)bh * TSEQ + (wq0 + lr)) * DHEAD + lg * 8;
    qf0 = scale8(*(const bf16x8*)(qrow), SCL);
    qf1 = scale8(*(const bf16x8*)(qrow + 32), SCL);
  }

  f32x4 acc[4];
#pragma unroll
  for (int df = 0; df < 4; df++) acc[df] = f32x4{0.f, 0.f, 0.f, 0.f};
  float mrun = -1e30f, lrun = 0.f;

  const int ntiles = qblk + 1;
  const int srow = tid >> 3, sc8 = (tid & 7) << 3;   // staging: 8 lanes/row

  // prologue: tile 0 -> LDS buf0; issue tile 1 -> regs
  i32x4 kreg[2], vreg[2];
#pragma unroll
  for (int p = 0; p < 2; p++) {
    int row = p * 32 + srow;
    *(i32x4*)&Ks[0][row][sc8] = *(const i32x4*)(kb + ((size_t)bh * TSEQ + row) * DHEAD + sc8);
    *(i32x4*)&Vs[0][row][sc8] = *(const i32x4*)(vT + ((size_t)bh * DHEAD + row) * TSEQ + sc8);
  }
#pragma unroll
  for (int p = 0; p < 2; p++) {
    int row = p * 32 + srow;
    kreg[p] = *(const i32x4*)(kb + ((size_t)bh * TSEQ + 64 + row) * DHEAD + sc8);
    vreg[p] = *(const i32x4*)(vT + ((size_t)bh * DHEAD + row) * TSEQ + 64 + sc8);
  }

  int c = 0;
  for (int kt = 0; kt < ntiles; kt++) {
    const int kbase = kt * 64;
    __syncthreads();   // buf[c] staged; prior reads of buf[c^1] done

    // S^T = K Q^T on buf[c] : 8 MFMA  (s[st]: k-rows st*16+lg*4+j, q-col lr)
    f32x4 s[4];
#pragma unroll
    for (int st = 0; st < 4; st++) {
      bf16x8 kf0 = *(const bf16x8*)&Ks[c][st * 16 + lr][lg * 8];
      bf16x8 kf1 = *(const bf16x8*)&Ks[c][st * 16 + lr][32 + lg * 8];
      f32x4 z = f32x4{0.f, 0.f, 0.f, 0.f};
      z = MFMA16(kf0, qf0, z);
      z = MFMA16(kf1, qf1, z);
      s[st] = z;
    }

    // stage tile kt+1 into buf[c^1] (vmcnt wait hides under QK MFMAs)
    if (kt + 1 < ntiles) {
#pragma unroll
      for (int p = 0; p < 2; p++) {
        int row = p * 32 + srow;
        *(i32x4*)&Ks[c ^ 1][row][sc8] = kreg[p];
        *(i32x4*)&Vs[c ^ 1][row][sc8] = vreg[p];
      }
    }
    // issue prefetch of tile kt+2
    if (kt + 2 < ntiles) {
      const int nb = kbase + 128;
#pragma unroll
      for (int p = 0; p < 2; p++) {
        int row = p * 32 + srow;
        kreg[p] = *(const i32x4*)(kb + ((size_t)bh * TSEQ + nb + row) * DHEAD + sc8);
        vreg[p] = *(const i32x4*)(vT + ((size_t)bh * DHEAD + row) * TSEQ + nb + sc8);
      }
    }

    // ---- online softmax: lane owns q = wq0 + lr; 16 k-values in-lane ----
    float mt = -1e30f;
    if (kt == ntiles - 1) {              // only the last tile is diagonal
      const int qg = wq0 + lr;
#pragma unroll
      for (int st = 0; st < 4; st++)
#pragma unroll
        for (int j = 0; j < 4; j++) {
          int kg = kbase + st * 16 + lg * 4 + j;
          float v = (kg <= qg) ? s[st][j] : -1e30f;
          s[st][j] = v;
          mt = fmaxf(mt, v);
        }
    } else {
#pragma unroll
      for (int st = 0; st < 4; st++)
#pragma unroll
        for (int j = 0; j < 4; j++) mt = fmaxf(mt, s[st][j]);
    }
    mt = fmaxf(mt, __shfl_xor(mt, 16));
    mt = fmaxf(mt, __shfl_xor(mt, 32));
    if (!__all(mt <= mrun)) {            // T13: skip rescale when max stable
      float mnew = fmaxf(mrun, mt);
      float al = __builtin_amdgcn_exp2f(mrun - mnew);
#pragma unroll
      for (int df = 0; df < 4; df++)
#pragma unroll
        for (int j = 0; j < 4; j++) acc[df][j] *= al;
      lrun *= al;
      mrun = mnew;
    }
    float rs = 0.f;
#pragma unroll
    for (int st = 0; st < 4; st++)
#pragma unroll
      for (int j = 0; j < 4; j++) {
        float p = __builtin_amdgcn_exp2f(s[st][j] - mrun);
        s[st][j] = p;
        rs += p;
      }
    rs += __shfl_xor(rs, 16);
    rs += __shfl_xor(rs, 32);
    lrun += rs;

    // ---- P -> PV B-frags, in-register butterfly ----
    uint32_t W[4][2];
#pragma unroll
    for (int st = 0; st < 4; st++) {
      W[st][0] = cvt_pk_bf16(s[st][0], s[st][1]);
      W[st][1] = cvt_pk_bf16(s[st][2], s[st][3]);
    }
    uint32_t Ka[2], Kb[2], Xa[2], Xb[2];
#pragma unroll
    for (int h = 0; h < 2; h++) {
      uint32_t S1a = b1 ? W[0][h] : W[1][h];    // st = b1^1
      uint32_t S1b = b1 ? W[2][h] : W[3][h];    // st = 2+b1^1
      Xa[h] = __shfl_xor(S1a, 32);              // recv: partner-group W[b1]
      Xb[h] = __shfl_xor(S1b, 32);              // recv: partner-group W[2+b1]
      Ka[h] = b1 ? W[1][h] : W[0][h];           // keep: own W[b1]
      Kb[h] = b1 ? W[3][h] : W[2][h];           // keep: own W[2+b1]
    }
    const bool e = (b0 == b1);
    uint32_t Ta[2], Tb[2], Ra[2], Rb[2];
#pragma unroll
    for (int h = 0; h < 2; h++) {
      uint32_t Cah = e ? Xa[h] : Ka[h];
      uint32_t Cbh = e ? Xb[h] : Kb[h];
      Ta[h] = e ? Ka[h] : Xa[h];
      Tb[h] = e ? Kb[h] : Xb[h];
      Ra[h] = __shfl_xor(Cah, 16);
      Rb[h] = __shfl_xor(Cbh, 16);
    }
    u32x4 w0, w1;
    w0[0] = b0 ? Ra[0] : Ta[0];  w0[1] = b0 ? Ra[1] : Ta[1];
    w0[2] = b0 ? Ta[0] : Ra[0];  w0[3] = b0 ? Ta[1] : Ra[1];
    w1[0] = b0 ? Rb[0] : Tb[0];  w1[1] = b0 ? Rb[1] : Tb[1];
    w1[2] = b0 ? Tb[0] : Rb[0];  w1[3] = b0 ? Tb[1] : Rb[1];
    bf16x8 pf0 = __builtin_bit_cast(bf16x8, w0);   // B-frag, k = lg*8..+7
    bf16x8 pf1 = __builtin_bit_cast(bf16x8, w1);   // B-frag, k = 32+lg*8..+7

    // y^T += V^T P on buf[c] : 8 MFMA
#pragma unroll
    for (int df = 0; df < 4; df++) {
      bf16x8 vf0 = *(const bf16x8*)&Vs[c][df * 16 + lr][lg * 8];
      bf16x8 vf1 = *(const bf16x8*)&Vs[c][df * 16 + lr][32 + lg * 8];
      acc[df] = MFMA16(vf0, pf0, acc[df]);
      acc[df] = MFMA16(vf1, pf1, acc[df]);
    }
    c ^= 1;
  }

  // epilogue: y = acc / l -> yb[b][t][h*64+d]
  const int b = bh >> 4, h = bh & 15;
  float inv = 1.f / lrun;
  int tg = wq0 + lr;
#pragma unroll
  for (int df = 0; df < 4; df++) {
    u16x4 o;
#pragma unroll
    for (int j = 0; j < 4; j++) o[j] = bf16r(acc[df][j] * inv);
    *(u16x4*)&yb[((size_t)b * TSEQ + tg) * CEMB + h * 64 + df * 16 + lg * 4] = o;
  }
}

// ---------------- proj GEMM ----------------
__global__ __launch_bounds__(256, 2) void proj_gemm(const u16* __restrict__ yb,
                                                    const u16* __restrict__ WpT,
                                                    const float* __restrict__ b_proj,
                                                    float* __restrict__ out) {
  __shared__ u16 AsU[2 * 128 * 32];
  __shared__ u16 BsU[2 * 128 * 32];
  const int m0 = blockIdx.y * 128, n0 = blockIdx.x * 128;
  f32x4 acc[4][4];
  gemm_mainloop(yb, WpT, CEMB, m0, n0, AsU, BsU, acc);

  const int tid = threadIdx.x;
  const int wv = tid >> 6, ln = tid & 63, lr = ln & 15, lg = ln >> 4;
  const int wr = (wv >> 1) * 64, wc = (wv & 1) * 64;
  for (int mi = 0; mi < 4; mi++)
    for (int ni = 0; ni < 4; ni++) {
      int col = n0 + wc + ni * 16 + lr;
      float bias = b_proj[col];
      for (int j = 0; j < 4; j++) {
        int m = m0 + wr + mi * 16 + lg * 4 + j;
        out[(size_t)m * CEMB + col] = acc[mi][ni][j] + bias;
      }
    }
}

// ---------------- launch ----------------
extern "C" void kernel_launch(void* const* d_in, const int* in_sizes, int n_in,
                              void* d_out, int out_size, void* d_ws, size_t ws_size,
                              hipStream_t stream) {
  const float* x      = (const float*)d_in[0];
  const float* W_attn = (const float*)d_in[1];
  const float* b_attn = (const float*)d_in[2];
  const float* W_proj = (const float*)d_in[3];
  const float* b_proj = (const float*)d_in[4];
  float* out = (float*)d_out;
  char* ws = (char*)d_ws;

  u16* xb  = (u16*)(ws);                 //  8 MB  [4096][1024] bf16
  u16* WaT = (u16*)(ws + 8388608);       //  6 MB  [3072][1024]
  u16* WpT = (u16*)(ws + 14680064);      //  2 MB  [1024][1024]
  u16* qb  = (u16*)(ws + 16777216);      //  8 MB  [BH][T][D]
  u16* kb  = (u16*)(ws + 25165824);      //  8 MB  [BH][T][D]
  u16* vT  = (u16*)(ws + 33554432);      //  8 MB  [BH][D][T]
  u16* yb  = (u16*)(ws + 41943040);      //  8 MB  [B][T][C]

  hipLaunchKernelGGL(prep, dim3(8192), dim3(256), 0, stream, x, xb, W_attn, WaT, W_proj, WpT);
  hipLaunchKernelGGL(qkv_gemm, dim3(24, 32), dim3(256), 0, stream, xb, WaT, b_attn, qb, kb, vT);
  hipLaunchKernelGGL(attn, dim3(1024), dim3(256), 0, stream, qb, kb, vT, yb);
  hipLaunchKernelGGL(proj_gemm, dim3(8, 32), dim3(256), 0, stream, yb, WpT, b_proj, out);
}